// Round 7
// baseline (176.573 us; speedup 1.0000x reference)
//
#include <hip/hip_runtime.h>
#include <stdint.h>

#define N_ANCH 147456
#define NGT 128
#define LIST_CAP 512

// d_ws layout: lab (N_ANCH bytes) | keys (N_ANCH u32) | ctl (W_WORDS u32)
// ctl word offsets (ctl byte base = 737280, 8B-aligned):
#define W_TICK2   0      // K2 ticket
#define W_TICK3   1      // K3 ticket
#define W_SEL     2      // 2ch x 6 {B, cumAbove, keep, keepAll, -, -}
#define W_LCNT    14     // 2 list counters
#define W_LIST    16     // 2 x 512 u64 sortkeys (2048 words, byte +64: 8B-aligned)
#define W_COARSE  2064   // 2 x 4096 histogram
#define W_GTMAX   10256  // 128 u64 (byte +41024: 8B-aligned)
#define W_WORDS   10512

__constant__ float c_base[9][4] = {
  {-84.f,-40.f,99.f,55.f},     // r=0.5 s=8
  {-176.f,-88.f,191.f,103.f},  // r=0.5 s=16
  {-360.f,-184.f,375.f,199.f}, // r=0.5 s=32
  {-56.f,-56.f,71.f,71.f},     // r=1   s=8
  {-120.f,-120.f,135.f,135.f}, // r=1   s=16
  {-248.f,-248.f,263.f,263.f}, // r=1   s=32
  {-36.f,-80.f,51.f,95.f},     // r=2   s=8
  {-80.f,-168.f,95.f,183.f},   // r=2   s=16
  {-168.f,-344.f,183.f,359.f}, // r=2   s=32
};

__host__ __device__ inline uint32_t rotl32(uint32_t v, int d){ return (v<<d)|(v>>(32-d)); }

// JAX Threefry-2x32, 20 rounds
__host__ __device__ inline void tf2x32(uint32_t k0, uint32_t k1, uint32_t x0, uint32_t x1,
                                       uint32_t* o0, uint32_t* o1){
  uint32_t ks0=k0, ks1=k1, ks2=k0^k1^0x1BD11BDAu;
  x0 += ks0; x1 += ks1;
  #define TFR(r) { x0 += x1; x1 = rotl32(x1,(r)); x1 ^= x0; }
  TFR(13) TFR(15) TFR(26) TFR(6)   x0+=ks1; x1+=ks2+1u;
  TFR(17) TFR(29) TFR(16) TFR(24)  x0+=ks2; x1+=ks0+2u;
  TFR(13) TFR(15) TFR(26) TFR(6)   x0+=ks0; x1+=ks1+3u;
  TFR(17) TFR(29) TFR(16) TFR(24)  x0+=ks1; x1+=ks2+4u;
  TFR(13) TFR(15) TFR(26) TFR(6)   x0+=ks2; x1+=ks0+5u;
  #undef TFR
  *o0=x0; *o1=x1;
}

// jax_threefry_partitionable=True: bits(j) = o0^o1 of enc(0,j); key = top 23 bits
__device__ inline uint32_t rand_m23(uint32_t k0, uint32_t k1, uint32_t j){
  uint32_t a, b;
  tf2x32(k0, k1, 0u, j, &a, &b);
  return (a ^ b) >> 9;
}

__device__ inline uint32_t aload(const uint32_t* p){
  return __hip_atomic_load(p, __ATOMIC_RELAXED, __HIP_MEMORY_SCOPE_AGENT);
}
__device__ inline unsigned long long aload64(const unsigned long long* p){
  return __hip_atomic_load(p, __ATOMIC_RELAXED, __HIP_MEMORY_SCOPE_AGENT);
}

// IoU with +1 convention; __fmul_rn pins rounding so K1/K2 agree bitwise
__device__ inline float iou_box(float ax1,float ay1,float ax2,float ay2,
                                float bx1,float by1,float bx2,float by2){
  float iw = fminf(ax2,bx2) - fmaxf(ax1,bx1) + 1.0f; iw = fmaxf(iw, 0.0f);
  float ih = fminf(ay2,by2) - fmaxf(ay1,by1) + 1.0f; ih = fmaxf(ih, 0.0f);
  float inter = __fmul_rn(iw, ih);
  float areaA = __fmul_rn(ax2-ax1+1.0f, ay2-ay1+1.0f);
  float areaB = __fmul_rn(bx2-bx1+1.0f, by2-by1+1.0f);
  return inter / ((areaA + areaB) - inter);
}

// K1: zero ctl; per-anchor max/argmax over gt -> labels, Threefry key, targets
__global__ __launch_bounds__(256) void k1_anchor(const float* __restrict__ gt,
                                                 const float* __restrict__ meta,
                                                 signed char* __restrict__ lab,
                                                 uint32_t* __restrict__ keys,
                                                 uint32_t* __restrict__ ctl,
                                                 float* __restrict__ out,
                                                 uint32_t pk0,uint32_t pk1,
                                                 uint32_t nk0,uint32_t nk1){
  __shared__ float4 sg[NGT];
  for (int t = threadIdx.x; t < NGT; t += 256)
    sg[t] = reinterpret_cast<const float4*>(gt)[t];
  __syncthreads();
  int i = blockIdx.x*256 + threadIdx.x;
  if (i < W_WORDS) ctl[i] = 0;   // K1 never reads ctl; later kernels see zeros (boundary)
  float W = meta[1], H = meta[0];
  int k = i / 9; int t9 = i - k*9;
  float sx = 16.0f * (float)(k & 127);
  float sy = 16.0f * (float)(k >> 7);
  float ax1 = c_base[t9][0] + sx, ay1 = c_base[t9][1] + sy;
  float ax2 = c_base[t9][2] + sx, ay2 = c_base[t9][3] + sy;
  bool inside = (ax1 >= 0.0f) && (ay1 >= 0.0f) && (ax2 < W) && (ay2 < H);
  float best = -1.0f; int arg = 0;   // outside: overlaps all -1 -> argmax 0
  if (inside){
    best = -2.0f;
    for (int g = 0; g < NGT; ++g){
      float4 G = sg[g];
      float ov = iou_box(ax1,ay1,ax2,ay2, G.x,G.y,G.z,G.w);
      if (ov > best){ best = ov; arg = g; }   // strict > = first-occurrence argmax
    }
  }
  signed char L = -1;
  if (best >= 0.7f) L = 1;
  else if (inside && best < 0.3f) L = 0;
  lab[i] = L;
  if (L >= 0)
    keys[i] = (L==1) ? rand_m23(pk0,pk1,(uint32_t)i) : rand_m23(nk0,nk1,(uint32_t)i);
  float4 t4 = make_float4(0.f, 0.f, 0.f, 0.f);
  if (inside){
    float4 G = sg[arg];
    float ew = ax2-ax1+1.0f, eh = ay2-ay1+1.0f;
    float ecx = ax1 + 0.5f*ew, ecy = ay1 + 0.5f*eh;
    float gw = G.z-G.x+1.0f, gh = G.w-G.y+1.0f;
    float gcx = G.x + 0.5f*gw, gcy = G.y + 0.5f*gh;
    t4.x = (gcx-ecx)/ew; t4.y = (gcy-ecy)/eh;
    t4.z = logf(gw/ew);  t4.w = logf(gh/eh);
  }
  *reinterpret_cast<float4*>(out + N_ANCH + 4*(size_t)i) = t4;
}

// K2: per-gt argmax slices + per-slice anchor histogram; last block:
// mark winners (k2b) + histogram deltas + counts/coarse-boundary (k4).
__global__ __launch_bounds__(256) void k2_gtmax(const float* __restrict__ gt,
                                                const float* __restrict__ meta,
                                                signed char* __restrict__ lab,
                                                uint32_t* __restrict__ keys,
                                                uint32_t* __restrict__ ctl,
                                                uint32_t pk0, uint32_t pk1){
  unsigned long long* gmax = (unsigned long long*)(ctl + W_GTMAX);
  int g = blockIdx.x >> 3, slice = blockIdx.x & 7;
  float bx1=gt[4*g], by1=gt[4*g+1], bx2=gt[4*g+2], by2=gt[4*g+3];
  float W = meta[1], H = meta[0];
  float a0[9],a1[9],a2[9],a3[9];
  #pragma unroll
  for (int t=0;t<9;++t){ a0[t]=c_base[t][0]; a1[t]=c_base[t][1];
                         a2[t]=c_base[t][2]; a3[t]=c_base[t][3]; }
  float best = -2.0f; int bi = 0;
  int kbase = slice*2048 + threadIdx.x;
  #pragma unroll
  for (int j = 0; j < 8; ++j){
    int k = kbase + j*256;
    float sx = 16.0f * (float)(k & 127);
    float sy = 16.0f * (float)(k >> 7);
    #pragma unroll
    for (int t = 0; t < 9; ++t){
      float ax1=a0[t]+sx, ay1=a1[t]+sy, ax2=a2[t]+sx, ay2=a3[t]+sy;
      bool inside = (ax1 >= 0.0f) && (ay1 >= 0.0f) && (ax2 < W) && (ay2 < H);
      float ov = inside ? iou_box(ax1,ay1,ax2,ay2,bx1,by1,bx2,by2) : -1.0f;
      if (ov > best){ best = ov; bi = k*9 + t; }   // j,t ascending -> min idx on tie
    }
  }
  unsigned long long p = 0ull;
  if (best >= 0.0f)
    p = ((unsigned long long)__float_as_uint(best) << 32) | (uint32_t)(~(uint32_t)bi);
  __shared__ unsigned long long sred[256];
  sred[threadIdx.x] = p;
  __syncthreads();
  for (int s = 128; s > 0; s >>= 1){
    if ((int)threadIdx.x < s){
      unsigned long long q = sred[threadIdx.x + s];
      if (q > sred[threadIdx.x]) sred[threadIdx.x] = q;
    }
    __syncthreads();
  }
  if (threadIdx.x == 0 && sred[0]) atomicMax(&gmax[g], sred[0]);

  // part 2: coarse histogram for this block's 144-anchor slice (lab/keys from K1)
  int ai = blockIdx.x*144 + threadIdx.x;
  if (threadIdx.x < 144){
    int L = lab[ai];
    if (L >= 0){
      int ch = (L==1) ? 0 : 1;
      atomicAdd(&ctl[W_COARSE + ch*4096 + (keys[ai]>>11)], 1u);
    }
  }

  // last-block tail
  __threadfence();
  __shared__ int amLast;
  if (threadIdx.x == 0)
    amLast = (atomicAdd(&ctl[W_TICK2], 1u) == (uint32_t)(gridDim.x - 1));
  __syncthreads();
  if (!amLast) return;
  __threadfence();

  int tid = threadIdx.x;
  __shared__ uint32_t widx[NGT], wkey[NGT];
  if (tid < NGT){
    unsigned long long q = aload64(&gmax[tid]);
    uint32_t idx = q ? ~(uint32_t)(q & 0xFFFFFFFFull) : 0xFFFFFFFFu;
    widx[tid] = idx;
    wkey[tid] = (idx != 0xFFFFFFFFu) ? rand_m23(pk0, pk1, idx) : 0u;
  }
  __syncthreads();
  if (tid < NGT && widx[tid] != 0xFFFFFFFFu){
    bool resp = true;                       // dedup duplicate winners: first g owns
    for (int g2 = 0; g2 < tid; ++g2) if (widx[g2] == widx[tid]) { resp = false; break; }
    if (resp){
      uint32_t idx = widx[tid];
      int oldL = lab[idx];
      if (oldL != 1){
        if (oldL == 0) atomicSub(&ctl[W_COARSE + 4096 + (keys[idx]>>11)], 1u);
        atomicAdd(&ctl[W_COARSE + (wkey[tid]>>11)], 1u);
        lab[idx] = 1;
        keys[idx] = wkey[tid];
      }
    }
  }
  __syncthreads();
  __threadfence();

  // counts + keep + coarse boundary bin (k4)
  __shared__ uint32_t gsum[256];
  __shared__ uint32_t scnt[2], selG[2], selCum[2], selKeep[2], selAll[2];
  __shared__ uint32_t binbuf[2][32];
  {
    int ch = tid >> 7, grp = tid & 127;
    const uint32_t* hist = ctl + W_COARSE + ch*4096;
    uint32_t s = 0;
    #pragma unroll
    for (int b = 0; b < 32; ++b) s += aload(&hist[grp*32 + b]);
    gsum[tid] = s;
  }
  __syncthreads();
  if (tid < 2){
    uint32_t cnt = 0;
    for (int q = 0; q < 128; ++q) cnt += gsum[tid*128 + q];
    scnt[tid] = cnt;
  }
  __syncthreads();
  if (tid < 2){
    int c = tid;
    uint32_t keepP = scnt[0] < 128u ? scnt[0] : 128u;
    uint32_t keep  = (c==0) ? keepP
                            : ((scnt[1] < 256u-keepP) ? scnt[1] : 256u-keepP);
    selKeep[c] = keep;
    if (keep >= scnt[c]){ selAll[c] = 1u; selG[c] = 0u; selCum[c] = 0u; }
    else {
      selAll[c] = 0u;
      uint32_t cum = 0; int G = 0;
      for (int q = 127; q >= 0; --q){
        uint32_t gc = gsum[c*128 + q];
        if (cum + gc >= keep){ G = q; break; }
        cum += gc;
      }
      selG[c] = (uint32_t)G; selCum[c] = cum;
    }
  }
  __syncthreads();
  if (tid < 64){
    int c = tid >> 5, b = tid & 31;
    if (!selAll[c]) binbuf[c][b] = aload(&ctl[W_COARSE + c*4096 + selG[c]*32 + b]);
  }
  __syncthreads();
  if (tid < 2){
    int c = tid;
    uint32_t* sel = ctl + W_SEL + c*6;
    sel[2] = selKeep[c]; sel[3] = selAll[c];
    if (!selAll[c]){
      uint32_t keep = selKeep[c], cum = selCum[c];
      int G = (int)selG[c], B = G*32;
      for (int b = 31; b >= 0; --b){
        uint32_t bc = binbuf[c][b];
        if (cum + bc >= keep){ B = G*32 + b; break; }
        cum += bc;
      }
      sel[0] = (uint32_t)B; sel[1] = cum;
    }
  }
}

// K3: final label write; boundary-bin candidates collected; last block sorts
// candidates by (key desc, idx asc) and writes them (k5+k6+k7+k8).
__global__ __launch_bounds__(256) void k3_final(const signed char* __restrict__ lab,
                                                const uint32_t* __restrict__ keys,
                                                float* __restrict__ out,
                                                uint32_t* __restrict__ ctl){
  int i = blockIdx.x*256 + threadIdx.x;
  int L = lab[i];
  float v = (float)L;
  int ch = (L==1) ? 0 : (L==0) ? 1 : -1;
  bool skip = false;
  if (ch >= 0){
    const uint32_t* sel = ctl + W_SEL + ch*6;
    if (!sel[3]){
      uint32_t m = keys[i], b = m >> 11, B = sel[0];
      if (b < B) v = -1.0f;
      else if (b == B){
        uint32_t pos = atomicAdd(&ctl[W_LCNT + ch], 1u);
        if (pos < LIST_CAP){
          unsigned long long sk = ((unsigned long long)(m ^ 0x7FFFFFu) << 32) | (uint32_t)i;
          __hip_atomic_store((unsigned long long*)(ctl + W_LIST) + ch*LIST_CAP + pos,
                             sk, __ATOMIC_RELAXED, __HIP_MEMORY_SCOPE_AGENT);
          skip = true;                 // written by the tail
        } else v = -1.0f;              // statistically impossible overflow
      }
    }
  }
  if (!skip) out[i] = v;

  __threadfence();
  __shared__ int amLast;
  if (threadIdx.x == 0)
    amLast = (atomicAdd(&ctl[W_TICK3], 1u) == (uint32_t)(gridDim.x - 1));
  __syncthreads();
  if (!amLast) return;
  __threadfence();

  int tid = threadIdx.x;
  __shared__ unsigned long long sk[2][LIST_CAP];   // 8 KB
  __shared__ uint32_t ln[2];
  if (tid < 2){
    uint32_t n = aload(&ctl[W_LCNT + tid]);
    ln[tid] = n < LIST_CAP ? n : LIST_CAP;
  }
  __syncthreads();
  for (int c = 0; c < 2; ++c)
    for (int p = tid; p < (int)ln[c]; p += 256)
      sk[c][p] = aload64((unsigned long long*)(ctl + W_LIST) + c*LIST_CAP + p);
  __syncthreads();
  if (tid < 2){
    int c = tid, n = (int)ln[c];
    for (int a = 1; a < n; ++a){                   // insertion sort (n ~ 17)
      unsigned long long v2 = sk[c][a]; int b2 = a - 1;
      while (b2 >= 0 && sk[c][b2] > v2){ sk[c][b2+1] = sk[c][b2]; --b2; }
      sk[c][b2+1] = v2;
    }
  }
  __syncthreads();
  for (int c = 0; c < 2; ++c){
    uint32_t need = ctl[W_SEL + c*6 + 2] - ctl[W_SEL + c*6 + 1];  // keep - cumAbove
    float kv = (c==0) ? 1.0f : 0.0f;
    for (int p = tid; p < (int)ln[c]; p += 256){
      uint32_t idx = (uint32_t)(sk[c][p] & 0xFFFFFFFFull);
      out[idx] = ((uint32_t)p < need) ? kv : -1.0f;
    }
  }
}

extern "C" void kernel_launch(void* const* d_in, const int* in_sizes, int n_in,
                              void* d_out, int out_size, void* d_ws, size_t ws_size,
                              hipStream_t stream) {
  const float* gt   = (const float*)d_in[1];   // (1,128,4)
  const float* meta = (const float*)d_in[2];   // (1,3) = {H, W, scale}
  float* out = (float*)d_out;                  // labels (147456) + targets (147456*4)
  signed char* lab = (signed char*)d_ws;                                 // N_ANCH B
  uint32_t* keys = (uint32_t*)((char*)d_ws + N_ANCH);                    // N_ANCH u32
  uint32_t* ctl  = keys + N_ANCH;                                        // W_WORDS u32

  // jax.random.key(42) = (0,42); partitionable split: key_i = enc(0, i) outputs
  uint32_t a0,a1,b0,b1;
  tf2x32(0u, 42u, 0u, 0u, &a0, &a1);   // k1 (positives)
  tf2x32(0u, 42u, 0u, 1u, &b0, &b1);   // k2 (negatives)

  k1_anchor<<<576, 256, 0, stream>>>(gt, meta, lab, keys, ctl, out, a0, a1, b0, b1);
  k2_gtmax <<<NGT*8, 256, 0, stream>>>(gt, meta, lab, keys, ctl, a0, a1);
  k3_final <<<576, 256, 0, stream>>>(lab, keys, out, ctl);
}

// Round 8
// 126.786 us; speedup vs baseline: 1.3927x; 1.3927x over previous
//
#include <hip/hip_runtime.h>
#include <stdint.h>

#define N_ANCH 147456
#define NGT 128

// d_ws layout: lab (N_ANCH B) | keys (N_ANCH u32) | ctl (u32 words below).
// NOTHING needs zero-init: every word read is unconditionally written earlier
// in the same call by a prior kernel (plain disjoint stores, no atomics).
#define W_CNTS   0      // 576 x {cntPos, cntNeg}
#define W_SEL    1152   // 2ch x 4 {Tf, keep, keepAll, pad}
#define W_GMAX2  1160   // 1024 u64 slots (8B-aligned)
#define W_LCNT   3208   // 2 x 576 survivor counts
#define W_LIST   4360   // 2 x 576 x 256 u64 sortkeys
#define MAXSURV  4096

__constant__ float c_base[9][4] = {
  {-84.f,-40.f,99.f,55.f},     // r=0.5 s=8
  {-176.f,-88.f,191.f,103.f},  // r=0.5 s=16
  {-360.f,-184.f,375.f,199.f}, // r=0.5 s=32
  {-56.f,-56.f,71.f,71.f},     // r=1   s=8
  {-120.f,-120.f,135.f,135.f}, // r=1   s=16
  {-248.f,-248.f,263.f,263.f}, // r=1   s=32
  {-36.f,-80.f,51.f,95.f},     // r=2   s=8
  {-80.f,-168.f,95.f,183.f},   // r=2   s=16
  {-168.f,-344.f,183.f,359.f}, // r=2   s=32
};

__host__ __device__ inline uint32_t rotl32(uint32_t v, int d){ return (v<<d)|(v>>(32-d)); }

// JAX Threefry-2x32, 20 rounds
__host__ __device__ inline void tf2x32(uint32_t k0, uint32_t k1, uint32_t x0, uint32_t x1,
                                       uint32_t* o0, uint32_t* o1){
  uint32_t ks0=k0, ks1=k1, ks2=k0^k1^0x1BD11BDAu;
  x0 += ks0; x1 += ks1;
  #define TFR(r) { x0 += x1; x1 = rotl32(x1,(r)); x1 ^= x0; }
  TFR(13) TFR(15) TFR(26) TFR(6)   x0+=ks1; x1+=ks2+1u;
  TFR(17) TFR(29) TFR(16) TFR(24)  x0+=ks2; x1+=ks0+2u;
  TFR(13) TFR(15) TFR(26) TFR(6)   x0+=ks0; x1+=ks1+3u;
  TFR(17) TFR(29) TFR(16) TFR(24)  x0+=ks1; x1+=ks2+4u;
  TFR(13) TFR(15) TFR(26) TFR(6)   x0+=ks2; x1+=ks0+5u;
  #undef TFR
  *o0=x0; *o1=x1;
}

// jax_threefry_partitionable=True: bits(j) = o0^o1 of enc(0,j); key = top 23 bits
__device__ inline uint32_t rand_m23(uint32_t k0, uint32_t k1, uint32_t j){
  uint32_t a, b;
  tf2x32(k0, k1, 0u, j, &a, &b);
  return (a ^ b) >> 9;
}

// IoU with +1 convention; __fmul_rn pins rounding so both argmax passes agree bitwise
__device__ inline float iou_box(float ax1,float ay1,float ax2,float ay2,
                                float bx1,float by1,float bx2,float by2){
  float iw = fminf(ax2,bx2) - fmaxf(ax1,bx1) + 1.0f; iw = fmaxf(iw, 0.0f);
  float ih = fminf(ay2,by2) - fmaxf(ay1,by1) + 1.0f; ih = fmaxf(ih, 0.0f);
  float inter = __fmul_rn(iw, ih);
  float areaA = __fmul_rn(ax2-ax1+1.0f, ay2-ay1+1.0f);
  float areaB = __fmul_rn(bx2-bx1+1.0f, by2-by1+1.0f);
  return inter / ((areaA + areaB) - inter);
}

// kA: blocks <576: per-anchor labels/keys/targets + per-block counts.
//     blocks >=576: per-(gt,slice) argmax -> disjoint gmax2 slot (plain store).
__global__ __launch_bounds__(256) void kA(const float* __restrict__ gt,
                                          const float* __restrict__ meta,
                                          signed char* __restrict__ lab,
                                          uint32_t* __restrict__ keys,
                                          uint32_t* __restrict__ ctl,
                                          float* __restrict__ out,
                                          uint32_t pk0,uint32_t pk1,
                                          uint32_t nk0,uint32_t nk1){
  int bid = blockIdx.x;
  float W = meta[1], H = meta[0];
  if (bid < 576){
    __shared__ float4 sg[NGT];
    __shared__ uint32_t c0, c1;
    if (threadIdx.x == 0){ c0 = 0u; c1 = 0u; }
    for (int t = threadIdx.x; t < NGT; t += 256)
      sg[t] = reinterpret_cast<const float4*>(gt)[t];
    __syncthreads();
    int i = bid*256 + threadIdx.x;
    int k = i / 9; int t9 = i - k*9;
    float sx = 16.0f * (float)(k & 127);
    float sy = 16.0f * (float)(k >> 7);
    float ax1 = c_base[t9][0] + sx, ay1 = c_base[t9][1] + sy;
    float ax2 = c_base[t9][2] + sx, ay2 = c_base[t9][3] + sy;
    bool inside = (ax1 >= 0.0f) && (ay1 >= 0.0f) && (ax2 < W) && (ay2 < H);
    float best = -1.0f; int arg = 0;   // outside: overlaps all -1 -> argmax 0
    if (inside){
      best = -2.0f;
      for (int g = 0; g < NGT; ++g){
        float4 G = sg[g];
        float ov = iou_box(ax1,ay1,ax2,ay2, G.x,G.y,G.z,G.w);
        if (ov > best){ best = ov; arg = g; }   // strict > = first-occurrence argmax
      }
    }
    signed char L = -1;
    if (best >= 0.7f) L = 1;
    else if (inside && best < 0.3f) L = 0;
    lab[i] = L;
    if (L == 1){ keys[i] = rand_m23(pk0,pk1,(uint32_t)i); atomicAdd(&c0,1u); }
    else if (L == 0){ keys[i] = rand_m23(nk0,nk1,(uint32_t)i); atomicAdd(&c1,1u); }
    float4 t4 = make_float4(0.f, 0.f, 0.f, 0.f);
    if (inside){
      float4 G = sg[arg];
      float ew = ax2-ax1+1.0f, eh = ay2-ay1+1.0f;
      float ecx = ax1 + 0.5f*ew, ecy = ay1 + 0.5f*eh;
      float gw = G.z-G.x+1.0f, gh = G.w-G.y+1.0f;
      float gcx = G.x + 0.5f*gw, gcy = G.y + 0.5f*gh;
      t4.x = (gcx-ecx)/ew; t4.y = (gcy-ecy)/eh;
      t4.z = logf(gw/ew);  t4.w = logf(gh/eh);
    }
    *reinterpret_cast<float4*>(out + N_ANCH + 4*(size_t)i) = t4;
    __syncthreads();
    if (threadIdx.x == 0){
      ctl[W_CNTS + 2*bid]     = c0;
      ctl[W_CNTS + 2*bid + 1] = c1;
    }
  } else {
    int b2 = bid - 576;
    int g = b2 >> 3, slice = b2 & 7;
    float bx1=gt[4*g], by1=gt[4*g+1], bx2=gt[4*g+2], by2=gt[4*g+3];
    float a0[9],a1[9],a2[9],a3[9];
    #pragma unroll
    for (int t=0;t<9;++t){ a0[t]=c_base[t][0]; a1[t]=c_base[t][1];
                           a2[t]=c_base[t][2]; a3[t]=c_base[t][3]; }
    float best = -2.0f; int bi = 0;
    int kbase = slice*2048 + threadIdx.x;
    #pragma unroll
    for (int j = 0; j < 8; ++j){
      int k = kbase + j*256;
      float sx = 16.0f * (float)(k & 127);
      float sy = 16.0f * (float)(k >> 7);
      #pragma unroll
      for (int t = 0; t < 9; ++t){
        float ax1=a0[t]+sx, ay1=a1[t]+sy, ax2=a2[t]+sx, ay2=a3[t]+sy;
        bool inside = (ax1 >= 0.0f) && (ay1 >= 0.0f) && (ax2 < W) && (ay2 < H);
        float ov = inside ? iou_box(ax1,ay1,ax2,ay2,bx1,by1,bx2,by2) : -1.0f;
        if (ov > best){ best = ov; bi = k*9 + t; }   // ascending -> min idx on tie
      }
    }
    unsigned long long p = 0ull;
    if (best >= 0.0f)
      p = ((unsigned long long)__float_as_uint(best) << 32) | (uint32_t)(~(uint32_t)bi);
    __shared__ unsigned long long sred[256];
    sred[threadIdx.x] = p;
    __syncthreads();
    for (int s = 128; s > 0; s >>= 1){
      if ((int)threadIdx.x < s){
        unsigned long long q = sred[threadIdx.x + s];
        if (q > sred[threadIdx.x]) sred[threadIdx.x] = q;
      }
      __syncthreads();
    }
    if (threadIdx.x == 0)
      reinterpret_cast<unsigned long long*>(ctl + W_GMAX2)[b2] = sred[0];
  }
}

// kB (1 block): reduce gmax2, dedup winners, mark lab/keys, adjust counts,
// compute keep counts and conservative filter thresholds.
__global__ __launch_bounds__(256) void kB(signed char* __restrict__ lab,
                                          uint32_t* __restrict__ keys,
                                          uint32_t* __restrict__ ctl,
                                          uint32_t pk0, uint32_t pk1){
  int tid = threadIdx.x;
  __shared__ uint32_t widx[NGT];
  __shared__ int dP, dN;
  __shared__ unsigned long long red[256];
  if (tid == 0){ dP = 0; dN = 0; }
  if (tid < NGT){
    const unsigned long long* g2 = reinterpret_cast<const unsigned long long*>(ctl + W_GMAX2);
    unsigned long long best = 0ull;
    #pragma unroll
    for (int s = 0; s < 8; ++s){
      unsigned long long q = g2[tid*8 + s];
      if (q > best) best = q;
    }
    widx[tid] = best ? ~(uint32_t)(best & 0xFFFFFFFFull) : 0xFFFFFFFFu;
  }
  __syncthreads();
  if (tid < NGT && widx[tid] != 0xFFFFFFFFu){
    bool resp = true;                       // dedup: first gt owns a shared winner
    for (int g2 = 0; g2 < tid; ++g2) if (widx[g2] == widx[tid]){ resp = false; break; }
    if (resp){
      uint32_t idx = widx[tid];
      int oldL = lab[idx];
      if (oldL != 1){
        atomicAdd(&dP, 1);
        if (oldL == 0) atomicAdd(&dN, 1);
        lab[idx] = 1;
        keys[idx] = rand_m23(pk0, pk1, idx);
      }
    }
  }
  __syncthreads();
  // sum per-block counts (packed u64: no cross-carry, sums < 2^32)
  unsigned long long acc = 0ull;
  for (int b = tid; b < 576; b += 256)
    acc += ((unsigned long long)ctl[W_CNTS + 2*b] << 32) | ctl[W_CNTS + 2*b + 1];
  red[tid] = acc;
  __syncthreads();
  for (int s = 128; s > 0; s >>= 1){
    if (tid < s) red[tid] += red[tid + s];
    __syncthreads();
  }
  if (tid == 0){
    uint32_t cntP = (uint32_t)(red[0] >> 32) + (uint32_t)dP;
    uint32_t cntN = (uint32_t)(red[0] & 0xFFFFFFFFull) - (uint32_t)dN;
    uint32_t keepP = cntP < 128u ? cntP : 128u;
    uint32_t keepN = cntN < (256u - keepP) ? cntN : (256u - keepP);
    uint32_t cnts[2] = {cntP, cntN}, keeps[2] = {keepP, keepN};
    for (int c = 0; c < 2; ++c){
      uint32_t cnt = cnts[c], keep = keeps[c];
      uint32_t keepAll = (keep >= cnt) ? 1u : 0u;
      uint32_t Tf = 0u;
      if (!keepAll){
        unsigned long long slack = 8ull * keep;   // expected survivors ~8*keep
        if (slack < cnt)
          Tf = (uint32_t)((((unsigned long long)(cnt - slack)) << 23) / cnt);
      }
      ctl[W_SEL + c*4 + 0] = Tf;
      ctl[W_SEL + c*4 + 1] = keep;
      ctl[W_SEL + c*4 + 2] = keepAll;
    }
  }
}

// kC: write all labels except survivors; append survivors to per-block slots.
__global__ __launch_bounds__(256) void kC(const signed char* __restrict__ lab,
                                          const uint32_t* __restrict__ keys,
                                          float* __restrict__ out,
                                          uint32_t* __restrict__ ctl){
  __shared__ uint32_t lcnt[2];
  if (threadIdx.x < 2) lcnt[threadIdx.x] = 0u;
  __syncthreads();
  int bid = blockIdx.x;
  int i = bid*256 + threadIdx.x;
  int L = lab[i];
  if (L < 0){
    out[i] = -1.0f;
  } else {
    int ch = (L == 1) ? 0 : 1;
    uint32_t Tf      = ctl[W_SEL + ch*4 + 0];
    uint32_t keepAll = ctl[W_SEL + ch*4 + 2];
    if (keepAll){
      out[i] = (float)L;
    } else {
      uint32_t m = keys[i];
      if (m < Tf){
        out[i] = -1.0f;                       // provably below the cutoff
      } else {
        uint32_t pos = atomicAdd(&lcnt[ch], 1u);   // LDS atomic, cheap
        unsigned long long sk =
          ((unsigned long long)(m ^ 0x7FFFFFu) << 32) | (uint32_t)i;
        reinterpret_cast<unsigned long long*>(ctl + W_LIST)
          [(ch*576 + bid)*256 + pos] = sk;    // decided in kD
      }
    }
  }
  __syncthreads();
  if (threadIdx.x < 2)
    ctl[W_LCNT + threadIdx.x*576 + bid] = lcnt[threadIdx.x];
}

// kD (1 block): gather survivors, bitonic sort (key desc, idx asc), write labels.
__global__ __launch_bounds__(256) void kD(float* __restrict__ out,
                                          uint32_t* __restrict__ ctl){
  int tid = threadIdx.x;
  __shared__ unsigned long long skey[MAXSURV];   // 32 KB
  __shared__ uint32_t cbuf[576], pfx[577], seg[96];
  for (int c = 0; c < 2; ++c){
    uint32_t keep    = ctl[W_SEL + c*4 + 1];
    uint32_t keepAll = ctl[W_SEL + c*4 + 2];
    if (!keepAll){
      for (int b = tid; b < 576; b += 256) cbuf[b] = ctl[W_LCNT + c*576 + b];
      __syncthreads();
      if (tid < 96){
        uint32_t s = 0;
        for (int j = 0; j < 6; ++j) s += cbuf[tid*6 + j];
        seg[tid] = s;
      }
      __syncthreads();
      if (tid == 0){
        uint32_t r = 0;
        for (int t = 0; t < 96; ++t){ uint32_t v = seg[t]; seg[t] = r; r += v; }
        pfx[576] = r;
      }
      __syncthreads();
      if (tid < 96){
        uint32_t r = seg[tid];
        for (int j = 0; j < 6; ++j){ pfx[tid*6 + j] = r; r += cbuf[tid*6 + j]; }
      }
      __syncthreads();
      int n = (int)pfx[576]; if (n > MAXSURV) n = MAXSURV;
      int N2 = 1; while (N2 < n) N2 <<= 1;
      // gather
      const unsigned long long* list =
        reinterpret_cast<const unsigned long long*>(ctl + W_LIST) + (size_t)c*576*256;
      for (int b = tid; b < 576; b += 256){
        uint32_t cnum = cbuf[b], base = pfx[b];
        for (uint32_t j = 0; j < cnum; ++j){
          uint32_t p = base + j;
          if (p < (uint32_t)MAXSURV) skey[p] = list[b*256 + j];
        }
      }
      for (int p = n + tid; p < N2; p += 256) skey[p] = ~0ull;
      __syncthreads();
      // bitonic ascending: ((key^max)<<32 | idx) asc == key desc, idx asc
      for (int k = 2; k <= N2; k <<= 1){
        for (int j = k >> 1; j > 0; j >>= 1){
          for (int p = tid; p < N2; p += 256){
            int ixj = p ^ j;
            if (ixj > p){
              bool up = ((p & k) == 0);
              unsigned long long a = skey[p], b = skey[ixj];
              if ((a > b) == up){ skey[p] = b; skey[ixj] = a; }
            }
          }
          __syncthreads();
        }
      }
      float kv = (c == 0) ? 1.0f : 0.0f;
      for (int p = tid; p < n; p += 256){
        uint32_t idx = (uint32_t)(skey[p] & 0xFFFFFFFFull);
        out[idx] = ((uint32_t)p < keep) ? kv : -1.0f;
      }
    }
    __syncthreads();
  }
}

extern "C" void kernel_launch(void* const* d_in, const int* in_sizes, int n_in,
                              void* d_out, int out_size, void* d_ws, size_t ws_size,
                              hipStream_t stream) {
  const float* gt   = (const float*)d_in[1];   // (1,128,4)
  const float* meta = (const float*)d_in[2];   // (1,3) = {H, W, scale}
  float* out = (float*)d_out;                  // labels (147456) + targets (147456*4)
  signed char* lab = (signed char*)d_ws;
  uint32_t* keys = (uint32_t*)((char*)d_ws + N_ANCH);
  uint32_t* ctl  = keys + N_ANCH;

  // jax.random.key(42) = (0,42); partitionable split: key_i = enc(0, i) outputs
  uint32_t a0,a1,b0,b1;
  tf2x32(0u, 42u, 0u, 0u, &a0, &a1);   // k1 (positives)
  tf2x32(0u, 42u, 0u, 1u, &b0, &b1);   // k2 (negatives)

  kA<<<1600, 256, 0, stream>>>(gt, meta, lab, keys, ctl, out, a0, a1, b0, b1);
  kB<<<1, 256, 0, stream>>>(lab, keys, ctl, a0, a1);
  kC<<<576, 256, 0, stream>>>(lab, keys, out, ctl);
  kD<<<1, 256, 0, stream>>>(out, ctl);
}

// Round 9
// 70.034 us; speedup vs baseline: 2.5213x; 1.8103x over previous
//
#include <hip/hip_runtime.h>
#include <stdint.h>

#define N_ANCH 147456
#define NGT 128

// d_ws layout: lab (N_ANCH B) | keys (N_ANCH u32) | ctl (u32 words below).
// NOTHING needs zero-init: every word read is unconditionally written earlier
// in the same call by a prior kernel (plain disjoint stores, no atomics).
#define W_CNTS   0      // 576 x {cntPos, cntNeg}
#define W_SEL    1152   // 2ch x 4 {Tf, keep, keepAll, pad}
#define W_GMAX2  1160   // 1024 u64 slots (8B-aligned)
#define W_LCNT   3208   // 2 x 576 survivor counts
#define W_LIST   4360   // 2 x 576 x 256 u64 sortkeys
#define MAXSURV  2048

__constant__ float c_base[9][4] = {
  {-84.f,-40.f,99.f,55.f},     // r=0.5 s=8
  {-176.f,-88.f,191.f,103.f},  // r=0.5 s=16
  {-360.f,-184.f,375.f,199.f}, // r=0.5 s=32
  {-56.f,-56.f,71.f,71.f},     // r=1   s=8
  {-120.f,-120.f,135.f,135.f}, // r=1   s=16
  {-248.f,-248.f,263.f,263.f}, // r=1   s=32
  {-36.f,-80.f,51.f,95.f},     // r=2   s=8
  {-80.f,-168.f,95.f,183.f},   // r=2   s=16
  {-168.f,-344.f,183.f,359.f}, // r=2   s=32
};

__host__ __device__ inline uint32_t rotl32(uint32_t v, int d){ return (v<<d)|(v>>(32-d)); }

// JAX Threefry-2x32, 20 rounds
__host__ __device__ inline void tf2x32(uint32_t k0, uint32_t k1, uint32_t x0, uint32_t x1,
                                       uint32_t* o0, uint32_t* o1){
  uint32_t ks0=k0, ks1=k1, ks2=k0^k1^0x1BD11BDAu;
  x0 += ks0; x1 += ks1;
  #define TFR(r) { x0 += x1; x1 = rotl32(x1,(r)); x1 ^= x0; }
  TFR(13) TFR(15) TFR(26) TFR(6)   x0+=ks1; x1+=ks2+1u;
  TFR(17) TFR(29) TFR(16) TFR(24)  x0+=ks2; x1+=ks0+2u;
  TFR(13) TFR(15) TFR(26) TFR(6)   x0+=ks0; x1+=ks1+3u;
  TFR(17) TFR(29) TFR(16) TFR(24)  x0+=ks1; x1+=ks2+4u;
  TFR(13) TFR(15) TFR(26) TFR(6)   x0+=ks2; x1+=ks0+5u;
  #undef TFR
  *o0=x0; *o1=x1;
}

// jax_threefry_partitionable=True: bits(j) = o0^o1 of enc(0,j); key = top 23 bits
__device__ inline uint32_t rand_m23(uint32_t k0, uint32_t k1, uint32_t j){
  uint32_t a, b;
  tf2x32(k0, k1, 0u, j, &a, &b);
  return (a ^ b) >> 9;
}

// IoU with +1 convention; __fmul_rn pins rounding so both argmax passes agree bitwise
__device__ inline float iou_box(float ax1,float ay1,float ax2,float ay2,
                                float bx1,float by1,float bx2,float by2){
  float iw = fminf(ax2,bx2) - fmaxf(ax1,bx1) + 1.0f; iw = fmaxf(iw, 0.0f);
  float ih = fminf(ay2,by2) - fmaxf(ay1,by1) + 1.0f; ih = fmaxf(ih, 0.0f);
  float inter = __fmul_rn(iw, ih);
  float areaA = __fmul_rn(ax2-ax1+1.0f, ay2-ay1+1.0f);
  float areaB = __fmul_rn(bx2-bx1+1.0f, by2-by1+1.0f);
  return inter / ((areaA + areaB) - inter);
}

// kA: blocks <576: per-anchor labels/keys/targets + per-block counts.
//     blocks >=576: per-(gt,slice) argmax -> disjoint gmax2 slot (plain store).
__global__ __launch_bounds__(256) void kA(const float* __restrict__ gt,
                                          const float* __restrict__ meta,
                                          signed char* __restrict__ lab,
                                          uint32_t* __restrict__ keys,
                                          uint32_t* __restrict__ ctl,
                                          float* __restrict__ out,
                                          uint32_t pk0,uint32_t pk1,
                                          uint32_t nk0,uint32_t nk1){
  int bid = blockIdx.x;
  float W = meta[1], H = meta[0];
  if (bid < 576){
    __shared__ float4 sg[NGT];
    __shared__ uint32_t c0, c1;
    if (threadIdx.x == 0){ c0 = 0u; c1 = 0u; }
    for (int t = threadIdx.x; t < NGT; t += 256)
      sg[t] = reinterpret_cast<const float4*>(gt)[t];
    __syncthreads();
    int i = bid*256 + threadIdx.x;
    int k = i / 9; int t9 = i - k*9;
    float sx = 16.0f * (float)(k & 127);
    float sy = 16.0f * (float)(k >> 7);
    float ax1 = c_base[t9][0] + sx, ay1 = c_base[t9][1] + sy;
    float ax2 = c_base[t9][2] + sx, ay2 = c_base[t9][3] + sy;
    bool inside = (ax1 >= 0.0f) && (ay1 >= 0.0f) && (ax2 < W) && (ay2 < H);
    float best = -1.0f; int arg = 0;   // outside: overlaps all -1 -> argmax 0
    if (inside){
      best = -2.0f;
      for (int g = 0; g < NGT; ++g){
        float4 G = sg[g];
        float ov = iou_box(ax1,ay1,ax2,ay2, G.x,G.y,G.z,G.w);
        if (ov > best){ best = ov; arg = g; }   // strict > = first-occurrence argmax
      }
    }
    signed char L = -1;
    if (best >= 0.7f) L = 1;
    else if (inside && best < 0.3f) L = 0;
    lab[i] = L;
    if (L == 1){ keys[i] = rand_m23(pk0,pk1,(uint32_t)i); atomicAdd(&c0,1u); }
    else if (L == 0){ keys[i] = rand_m23(nk0,nk1,(uint32_t)i); atomicAdd(&c1,1u); }
    float4 t4 = make_float4(0.f, 0.f, 0.f, 0.f);
    if (inside){
      float4 G = sg[arg];
      float ew = ax2-ax1+1.0f, eh = ay2-ay1+1.0f;
      float ecx = ax1 + 0.5f*ew, ecy = ay1 + 0.5f*eh;
      float gw = G.z-G.x+1.0f, gh = G.w-G.y+1.0f;
      float gcx = G.x + 0.5f*gw, gcy = G.y + 0.5f*gh;
      t4.x = (gcx-ecx)/ew; t4.y = (gcy-ecy)/eh;
      t4.z = logf(gw/ew);  t4.w = logf(gh/eh);
    }
    *reinterpret_cast<float4*>(out + N_ANCH + 4*(size_t)i) = t4;
    __syncthreads();
    if (threadIdx.x == 0){
      ctl[W_CNTS + 2*bid]     = c0;
      ctl[W_CNTS + 2*bid + 1] = c1;
    }
  } else {
    int b2 = bid - 576;
    int g = b2 >> 3, slice = b2 & 7;
    float bx1=gt[4*g], by1=gt[4*g+1], bx2=gt[4*g+2], by2=gt[4*g+3];
    float a0[9],a1[9],a2[9],a3[9];
    #pragma unroll
    for (int t=0;t<9;++t){ a0[t]=c_base[t][0]; a1[t]=c_base[t][1];
                           a2[t]=c_base[t][2]; a3[t]=c_base[t][3]; }
    float best = -2.0f; int bi = 0;
    int kbase = slice*2048 + threadIdx.x;
    #pragma unroll
    for (int j = 0; j < 8; ++j){
      int k = kbase + j*256;
      float sx = 16.0f * (float)(k & 127);
      float sy = 16.0f * (float)(k >> 7);
      #pragma unroll
      for (int t = 0; t < 9; ++t){
        float ax1=a0[t]+sx, ay1=a1[t]+sy, ax2=a2[t]+sx, ay2=a3[t]+sy;
        bool inside = (ax1 >= 0.0f) && (ay1 >= 0.0f) && (ax2 < W) && (ay2 < H);
        float ov = inside ? iou_box(ax1,ay1,ax2,ay2,bx1,by1,bx2,by2) : -1.0f;
        if (ov > best){ best = ov; bi = k*9 + t; }   // ascending -> min idx on tie
      }
    }
    unsigned long long p = 0ull;
    if (best >= 0.0f)
      p = ((unsigned long long)__float_as_uint(best) << 32) | (uint32_t)(~(uint32_t)bi);
    __shared__ unsigned long long sred[256];
    sred[threadIdx.x] = p;
    __syncthreads();
    for (int s = 128; s > 0; s >>= 1){
      if ((int)threadIdx.x < s){
        unsigned long long q = sred[threadIdx.x + s];
        if (q > sred[threadIdx.x]) sred[threadIdx.x] = q;
      }
      __syncthreads();
    }
    if (threadIdx.x == 0)
      reinterpret_cast<unsigned long long*>(ctl + W_GMAX2)[b2] = sred[0];
  }
}

// kB (1 block): reduce gmax2, dedup winners, mark lab/keys, adjust counts,
// compute keep counts and conservative filter thresholds.
__global__ __launch_bounds__(256) void kB(signed char* __restrict__ lab,
                                          uint32_t* __restrict__ keys,
                                          uint32_t* __restrict__ ctl,
                                          uint32_t pk0, uint32_t pk1){
  int tid = threadIdx.x;
  __shared__ uint32_t widx[NGT];
  __shared__ int dP, dN;
  __shared__ unsigned long long red[256];
  if (tid == 0){ dP = 0; dN = 0; }
  if (tid < NGT){
    const unsigned long long* g2 = reinterpret_cast<const unsigned long long*>(ctl + W_GMAX2);
    unsigned long long best = 0ull;
    #pragma unroll
    for (int s = 0; s < 8; ++s){
      unsigned long long q = g2[tid*8 + s];
      if (q > best) best = q;
    }
    widx[tid] = best ? ~(uint32_t)(best & 0xFFFFFFFFull) : 0xFFFFFFFFu;
  }
  __syncthreads();
  if (tid < NGT && widx[tid] != 0xFFFFFFFFu){
    bool resp = true;                       // dedup: first gt owns a shared winner
    for (int g2 = 0; g2 < tid; ++g2) if (widx[g2] == widx[tid]){ resp = false; break; }
    if (resp){
      uint32_t idx = widx[tid];
      int oldL = lab[idx];
      if (oldL != 1){
        atomicAdd(&dP, 1);
        if (oldL == 0) atomicAdd(&dN, 1);
        lab[idx] = 1;
        keys[idx] = rand_m23(pk0, pk1, idx);
      }
    }
  }
  __syncthreads();
  // sum per-block counts (packed u64: no cross-carry, sums < 2^32)
  unsigned long long acc = 0ull;
  for (int b = tid; b < 576; b += 256)
    acc += ((unsigned long long)ctl[W_CNTS + 2*b] << 32) | ctl[W_CNTS + 2*b + 1];
  red[tid] = acc;
  __syncthreads();
  for (int s = 128; s > 0; s >>= 1){
    if (tid < s) red[tid] += red[tid + s];
    __syncthreads();
  }
  if (tid == 0){
    uint32_t cntP = (uint32_t)(red[0] >> 32) + (uint32_t)dP;
    uint32_t cntN = (uint32_t)(red[0] & 0xFFFFFFFFull) - (uint32_t)dN;
    uint32_t keepP = cntP < 128u ? cntP : 128u;
    uint32_t keepN = cntN < (256u - keepP) ? cntN : (256u - keepP);
    uint32_t cnts[2] = {cntP, cntN}, keeps[2] = {keepP, keepN};
    for (int c = 0; c < 2; ++c){
      uint32_t cnt = cnts[c], keep = keeps[c];
      uint32_t keepAll = (keep >= cnt) ? 1u : 0u;
      uint32_t Tf = 0u;
      if (!keepAll){
        unsigned long long slack = 4ull * keep;   // mean survivors ~4*keep (>=10 sigma margin)
        if (slack < cnt)
          Tf = (uint32_t)((((unsigned long long)(cnt - slack)) << 23) / cnt);
      }
      ctl[W_SEL + c*4 + 0] = Tf;
      ctl[W_SEL + c*4 + 1] = keep;
      ctl[W_SEL + c*4 + 2] = keepAll;
    }
  }
}

// kC: write all labels except survivors; append survivors to per-block slots.
__global__ __launch_bounds__(256) void kC(const signed char* __restrict__ lab,
                                          const uint32_t* __restrict__ keys,
                                          float* __restrict__ out,
                                          uint32_t* __restrict__ ctl){
  __shared__ uint32_t lcnt[2];
  if (threadIdx.x < 2) lcnt[threadIdx.x] = 0u;
  __syncthreads();
  int bid = blockIdx.x;
  int i = bid*256 + threadIdx.x;
  int L = lab[i];
  if (L < 0){
    out[i] = -1.0f;
  } else {
    int ch = (L == 1) ? 0 : 1;
    uint32_t Tf      = ctl[W_SEL + ch*4 + 0];
    uint32_t keepAll = ctl[W_SEL + ch*4 + 2];
    if (keepAll){
      out[i] = (float)L;
    } else {
      uint32_t m = keys[i];
      if (m < Tf){
        out[i] = -1.0f;                       // provably below the cutoff
      } else {
        uint32_t pos = atomicAdd(&lcnt[ch], 1u);   // LDS atomic, cheap
        unsigned long long sk =
          ((unsigned long long)(m ^ 0x7FFFFFu) << 32) | (uint32_t)i;
        reinterpret_cast<unsigned long long*>(ctl + W_LIST)
          [(ch*576 + bid)*256 + pos] = sk;    // decided in kD
      }
    }
  }
  __syncthreads();
  if (threadIdx.x < 2)
    ctl[W_LCNT + threadIdx.x*576 + bid] = lcnt[threadIdx.x];
}

// kD (1 block x 1024): gather survivors via LDS-atomic slots (order-free),
// rank-count (no sort, no barrier chains), write labels.
// sk asc == (key desc, idx asc) == argsort rank order; all sk distinct.
__global__ __launch_bounds__(1024) void kD(float* __restrict__ out,
                                           uint32_t* __restrict__ ctl){
  int tid = threadIdx.x;
  __shared__ unsigned long long skey[MAXSURV];   // 16 KB
  __shared__ uint32_t nctr;
  for (int c = 0; c < 2; ++c){
    uint32_t keep    = ctl[W_SEL + c*4 + 1];
    uint32_t keepAll = ctl[W_SEL + c*4 + 2];
    if (!keepAll){
      if (tid == 0) nctr = 0u;
      __syncthreads();
      if (tid < 576){
        uint32_t cnum = ctl[W_LCNT + c*576 + tid];
        if (cnum){
          uint32_t base = atomicAdd(&nctr, cnum);
          const unsigned long long* list =
            reinterpret_cast<const unsigned long long*>(ctl + W_LIST)
            + (size_t)(c*576 + tid)*256;
          for (uint32_t j = 0; j < cnum; ++j){
            uint32_t p = base + j;
            if (p < (uint32_t)MAXSURV) skey[p] = list[j];
          }
        }
      }
      __syncthreads();
      int n = (int)nctr; if (n > MAXSURV) n = MAXSURV;
      float kv = (c == 0) ? 1.0f : 0.0f;
      for (int p = tid; p < n; p += 1024){
        unsigned long long mine = skey[p];
        uint32_t r = 0;
        for (int j = 0; j < n; ++j) r += (skey[j] < mine) ? 1u : 0u;  // LDS broadcast
        uint32_t idx = (uint32_t)(mine & 0xFFFFFFFFull);
        out[idx] = (r < keep) ? kv : -1.0f;
      }
    }
    __syncthreads();
  }
}

extern "C" void kernel_launch(void* const* d_in, const int* in_sizes, int n_in,
                              void* d_out, int out_size, void* d_ws, size_t ws_size,
                              hipStream_t stream) {
  const float* gt   = (const float*)d_in[1];   // (1,128,4)
  const float* meta = (const float*)d_in[2];   // (1,3) = {H, W, scale}
  float* out = (float*)d_out;                  // labels (147456) + targets (147456*4)
  signed char* lab = (signed char*)d_ws;
  uint32_t* keys = (uint32_t*)((char*)d_ws + N_ANCH);
  uint32_t* ctl  = keys + N_ANCH;

  // jax.random.key(42) = (0,42); partitionable split: key_i = enc(0, i) outputs
  uint32_t a0,a1,b0,b1;
  tf2x32(0u, 42u, 0u, 0u, &a0, &a1);   // k1 (positives)
  tf2x32(0u, 42u, 0u, 1u, &b0, &b1);   // k2 (negatives)

  kA<<<1600, 256, 0, stream>>>(gt, meta, lab, keys, ctl, out, a0, a1, b0, b1);
  kB<<<1, 256, 0, stream>>>(lab, keys, ctl, a0, a1);
  kC<<<576, 256, 0, stream>>>(lab, keys, out, ctl);
  kD<<<1, 1024, 0, stream>>>(out, ctl);
}

// Round 10
// 63.336 us; speedup vs baseline: 2.7879x; 1.1057x over previous
//
#include <hip/hip_runtime.h>
#include <stdint.h>

#define N_ANCH 147456
#define NGT 128

// d_ws layout: lab (N_ANCH B) | keys (N_ANCH u32) | ctl (u32 words below).
// NOTHING needs zero-init: every word read is unconditionally written earlier
// in the same call by a prior kernel (plain disjoint stores, no atomics).
#define W_CNTS   0      // 576 x {cntPos, cntNeg}
#define W_SEL    1152   // 2ch x 4 {Tf, keep, keepAll, pad}  (written by kC blk0, read by kD)
#define W_GMAX2  1160   // 1024 u64 slots (8B-aligned)
#define W_LCNT   3208   // 2 x 576 survivor counts
#define W_LIST   4360   // 2 x 576 x 256 u64 sortkeys
#define MAXSURV  2048

__constant__ float c_base[9][4] = {
  {-84.f,-40.f,99.f,55.f},     // r=0.5 s=8
  {-176.f,-88.f,191.f,103.f},  // r=0.5 s=16
  {-360.f,-184.f,375.f,199.f}, // r=0.5 s=32
  {-56.f,-56.f,71.f,71.f},     // r=1   s=8
  {-120.f,-120.f,135.f,135.f}, // r=1   s=16
  {-248.f,-248.f,263.f,263.f}, // r=1   s=32
  {-36.f,-80.f,51.f,95.f},     // r=2   s=8
  {-80.f,-168.f,95.f,183.f},   // r=2   s=16
  {-168.f,-344.f,183.f,359.f}, // r=2   s=32
};
// exact per-type anchor areas (W*H, integers < 2^24 -> bitwise == __fmul_rn result)
__constant__ float c_areaA[9] = {
  17664.f, 70656.f, 282624.f,
  16384.f, 65536.f, 262144.f,
  15488.f, 61952.f, 247808.f,
};

__host__ __device__ inline uint32_t rotl32(uint32_t v, int d){ return (v<<d)|(v>>(32-d)); }

// JAX Threefry-2x32, 20 rounds
__host__ __device__ inline void tf2x32(uint32_t k0, uint32_t k1, uint32_t x0, uint32_t x1,
                                       uint32_t* o0, uint32_t* o1){
  uint32_t ks0=k0, ks1=k1, ks2=k0^k1^0x1BD11BDAu;
  x0 += ks0; x1 += ks1;
  #define TFR(r) { x0 += x1; x1 = rotl32(x1,(r)); x1 ^= x0; }
  TFR(13) TFR(15) TFR(26) TFR(6)   x0+=ks1; x1+=ks2+1u;
  TFR(17) TFR(29) TFR(16) TFR(24)  x0+=ks2; x1+=ks0+2u;
  TFR(13) TFR(15) TFR(26) TFR(6)   x0+=ks0; x1+=ks1+3u;
  TFR(17) TFR(29) TFR(16) TFR(24)  x0+=ks1; x1+=ks2+4u;
  TFR(13) TFR(15) TFR(26) TFR(6)   x0+=ks2; x1+=ks0+5u;
  #undef TFR
  *o0=x0; *o1=x1;
}

// jax_threefry_partitionable=True: bits(j) = o0^o1 of enc(0,j); key = top 23 bits
__device__ inline uint32_t rand_m23(uint32_t k0, uint32_t k1, uint32_t j){
  uint32_t a, b;
  tf2x32(k0, k1, 0u, j, &a, &b);
  return (a ^ b) >> 9;
}

// kA: blocks <576: per-anchor labels/keys/targets + per-block counts.
//     blocks >=576: per-(gt,slice) argmax -> disjoint gmax2 slot (plain store).
// IoU identities preserved bitwise vs reference: areas hoisted (same formula,
// same rounding), denom kept as (areaA + areaB) - inter, division kept IEEE;
// quick-reject (iw<=0||ih<=0 -> ov=+0) matches 0/denom = +0 exactly.
__global__ __launch_bounds__(256) void kA(const float* __restrict__ gt,
                                          const float* __restrict__ meta,
                                          signed char* __restrict__ lab,
                                          uint32_t* __restrict__ keys,
                                          uint32_t* __restrict__ ctl,
                                          float* __restrict__ out,
                                          uint32_t pk0,uint32_t pk1,
                                          uint32_t nk0,uint32_t nk1){
  int bid = blockIdx.x;
  float W = meta[1], H = meta[0];
  if (bid < 576){
    __shared__ float4 sg[NGT];
    __shared__ float  sB[NGT];
    __shared__ uint32_t c0, c1;
    if (threadIdx.x == 0){ c0 = 0u; c1 = 0u; }
    for (int t = threadIdx.x; t < NGT; t += 256){
      float4 G = reinterpret_cast<const float4*>(gt)[t];
      sg[t] = G;
      sB[t] = __fmul_rn(G.z - G.x + 1.0f, G.w - G.y + 1.0f);
    }
    __syncthreads();
    int i = bid*256 + threadIdx.x;
    int k = i / 9; int t9 = i - k*9;
    float sx = 16.0f * (float)(k & 127);
    float sy = 16.0f * (float)(k >> 7);
    float ax1 = c_base[t9][0] + sx, ay1 = c_base[t9][1] + sy;
    float ax2 = c_base[t9][2] + sx, ay2 = c_base[t9][3] + sy;
    float areaA = c_areaA[t9];
    bool inside = (ax1 >= 0.0f) && (ay1 >= 0.0f) && (ax2 < W) && (ay2 < H);
    float best = -1.0f; int arg = 0;   // outside: overlaps all -1 -> argmax 0
    if (inside){
      best = -2.0f;
      for (int g = 0; g < NGT; ++g){
        float4 G = sg[g];
        float iw = fminf(ax2,G.z) - fmaxf(ax1,G.x) + 1.0f;
        float ih = fminf(ay2,G.w) - fmaxf(ay1,G.y) + 1.0f;
        float ov = 0.0f;
        if (iw > 0.0f && ih > 0.0f){
          float inter = __fmul_rn(iw, ih);
          ov = inter / ((areaA + sB[g]) - inter);
        }
        if (ov > best){ best = ov; arg = g; }   // strict > = first-occurrence argmax
      }
    }
    signed char L = -1;
    if (best >= 0.7f) L = 1;
    else if (inside && best < 0.3f) L = 0;
    lab[i] = L;
    if (L == 1) keys[i] = rand_m23(pk0,pk1,(uint32_t)i);
    else if (L == 0) keys[i] = rand_m23(nk0,nk1,(uint32_t)i);
    unsigned long long b1 = __ballot(L == 1);
    unsigned long long b0 = __ballot(L == 0);
    if ((threadIdx.x & 63) == 0){
      if (b1) atomicAdd(&c0, (uint32_t)__popcll(b1));
      if (b0) atomicAdd(&c1, (uint32_t)__popcll(b0));
    }
    float4 t4 = make_float4(0.f, 0.f, 0.f, 0.f);
    if (inside){
      float4 G = sg[arg];
      float ew = ax2-ax1+1.0f, eh = ay2-ay1+1.0f;
      float ecx = ax1 + 0.5f*ew, ecy = ay1 + 0.5f*eh;
      float gw = G.z-G.x+1.0f, gh = G.w-G.y+1.0f;
      float gcx = G.x + 0.5f*gw, gcy = G.y + 0.5f*gh;
      t4.x = (gcx-ecx)/ew; t4.y = (gcy-ecy)/eh;
      t4.z = logf(gw/ew);  t4.w = logf(gh/eh);
    }
    *reinterpret_cast<float4*>(out + N_ANCH + 4*(size_t)i) = t4;
    __syncthreads();
    if (threadIdx.x == 0){
      ctl[W_CNTS + 2*bid]     = c0;
      ctl[W_CNTS + 2*bid + 1] = c1;
    }
  } else {
    int b2 = bid - 576;
    int g = b2 >> 3, slice = b2 & 7;
    float bx1=gt[4*g], by1=gt[4*g+1], bx2=gt[4*g+2], by2=gt[4*g+3];
    float areaB = __fmul_rn(bx2-bx1+1.0f, by2-by1+1.0f);
    float a0[9],a1[9],a2[9],a3[9];
    #pragma unroll
    for (int t=0;t<9;++t){ a0[t]=c_base[t][0]; a1[t]=c_base[t][1];
                           a2[t]=c_base[t][2]; a3[t]=c_base[t][3]; }
    float best = -2.0f; int bi = 0;
    int kbase = slice*2048 + threadIdx.x;
    #pragma unroll
    for (int j = 0; j < 8; ++j){
      int k = kbase + j*256;
      float sx = 16.0f * (float)(k & 127);
      float sy = 16.0f * (float)(k >> 7);
      #pragma unroll
      for (int t = 0; t < 9; ++t){
        float ax1=a0[t]+sx, ay1=a1[t]+sy, ax2=a2[t]+sx, ay2=a3[t]+sy;
        bool inside = (ax1 >= 0.0f) && (ay1 >= 0.0f) && (ax2 < W) && (ay2 < H);
        float iw = fminf(ax2,bx2) - fmaxf(ax1,bx1) + 1.0f;
        float ih = fminf(ay2,by2) - fmaxf(ay1,by1) + 1.0f;
        float ov = inside ? 0.0f : -1.0f;
        if (inside && iw > 0.0f && ih > 0.0f){
          float inter = __fmul_rn(iw, ih);
          ov = inter / ((c_areaA[t] + areaB) - inter);
        }
        if (ov > best){ best = ov; bi = k*9 + t; }   // ascending -> min idx on tie
      }
    }
    unsigned long long p = 0ull;
    if (best >= 0.0f)
      p = ((unsigned long long)__float_as_uint(best) << 32) | (uint32_t)(~(uint32_t)bi);
    __shared__ unsigned long long sred[256];
    sred[threadIdx.x] = p;
    __syncthreads();
    for (int s = 128; s > 0; s >>= 1){
      if ((int)threadIdx.x < s){
        unsigned long long q = sred[threadIdx.x + s];
        if (q > sred[threadIdx.x]) sred[threadIdx.x] = q;
      }
      __syncthreads();
    }
    if (threadIdx.x == 0)
      reinterpret_cast<unsigned long long*>(ctl + W_GMAX2)[b2] = sred[0];
  }
}

// kC: each block redundantly derives the kB state (winners, counts, Tf) from
// kA's outputs (L2-hot ~13KB), applies winners locally via an LDS flag table,
// writes final labels, and appends survivors. Block 0 persists W_SEL for kD.
// lab/keys are READ-ONLY here (no cross-block data mutation).
__global__ __launch_bounds__(256) void kC(const signed char* __restrict__ lab,
                                          const uint32_t* __restrict__ keys,
                                          float* __restrict__ out,
                                          uint32_t* __restrict__ ctl,
                                          uint32_t pk0, uint32_t pk1){
  int tid = threadIdx.x, bid = blockIdx.x;
  __shared__ uint32_t widx[NGT], wkey[NGT], wflag[256];
  __shared__ int sdP, sdN;
  __shared__ unsigned long long red[256];
  __shared__ uint32_t sel[6];     // 2ch x {Tf, keep, keepAll}
  __shared__ uint32_t lcnt[2];
  wflag[tid] = 0xFFFFFFFFu;
  if (tid == 0){ sdP = 0; sdN = 0; lcnt[0] = 0u; lcnt[1] = 0u; }
  if (tid < NGT){
    const unsigned long long* g2 =
      reinterpret_cast<const unsigned long long*>(ctl + W_GMAX2);
    unsigned long long best = 0ull;
    #pragma unroll
    for (int s = 0; s < 8; ++s){
      unsigned long long q = g2[tid*8 + s];
      if (q > best) best = q;
    }
    uint32_t idx = best ? ~(uint32_t)best : 0xFFFFFFFFu;
    widx[tid] = idx;
    wkey[tid] = (idx != 0xFFFFFFFFu) ? rand_m23(pk0, pk1, idx) : 0u;
  }
  // per-block counts (packed u64: no cross-carry, sums < 2^32)
  unsigned long long acc = 0ull;
  for (int b = tid; b < 576; b += 256)
    acc += ((unsigned long long)ctl[W_CNTS + 2*b] << 32) | ctl[W_CNTS + 2*b + 1];
  red[tid] = acc;
  __syncthreads();
  for (int s = 128; s > 0; s >>= 1){
    if (tid < s) red[tid] += red[tid + s];
    __syncthreads();
  }
  if (tid < NGT && widx[tid] != 0xFFFFFFFFu){
    uint32_t idx = widx[tid];
    if ((idx >> 8) == (uint32_t)bid) wflag[idx & 255u] = wkey[tid];
    bool resp = true;                     // dedup: first gt owns a shared winner
    for (int g = 0; g < tid; ++g) if (widx[g] == idx){ resp = false; break; }
    if (resp){
      int oldL = lab[idx];
      if (oldL != 1){ atomicAdd(&sdP, 1); if (oldL == 0) atomicAdd(&sdN, 1); }
    }
  }
  __syncthreads();
  if (tid == 0){
    uint32_t cntP = (uint32_t)(red[0] >> 32) + (uint32_t)sdP;
    uint32_t cntN = (uint32_t)red[0] - (uint32_t)sdN;
    uint32_t keepP = cntP < 128u ? cntP : 128u;
    uint32_t keepN = cntN < (256u - keepP) ? cntN : (256u - keepP);
    uint32_t cnts[2] = {cntP, cntN}, keeps[2] = {keepP, keepN};
    for (int c = 0; c < 2; ++c){
      uint32_t cnt = cnts[c], keep = keeps[c];
      uint32_t all = (keep >= cnt) ? 1u : 0u, Tf = 0u;
      if (!all){
        unsigned long long slack = 4ull * keep;   // mean survivors ~4*keep (>=10 sigma)
        if (slack < cnt)
          Tf = (uint32_t)((((unsigned long long)(cnt - slack)) << 23) / cnt);
      }
      sel[c*3+0] = Tf; sel[c*3+1] = keep; sel[c*3+2] = all;
    }
    if (bid == 0){
      for (int c = 0; c < 2; ++c){
        ctl[W_SEL + c*4 + 0] = sel[c*3+0];
        ctl[W_SEL + c*4 + 1] = sel[c*3+1];
        ctl[W_SEL + c*4 + 2] = sel[c*3+2];
      }
    }
  }
  __syncthreads();
  int i = bid*256 + tid;
  int L = lab[i];
  uint32_t wf = wflag[tid];
  uint32_t m = 0u;
  if (wf != 0xFFFFFFFFu){ L = 1; m = wf; }       // winner override (pos channel)
  else if (L >= 0) m = keys[i];
  if (L < 0){
    out[i] = -1.0f;
  } else {
    int ch = (L == 1) ? 0 : 1;
    if (sel[ch*3+2]){
      out[i] = (float)L;
    } else if (m < sel[ch*3+0]){
      out[i] = -1.0f;                      // provably below the cutoff
    } else {
      uint32_t pos = atomicAdd(&lcnt[ch], 1u);
      reinterpret_cast<unsigned long long*>(ctl + W_LIST)
        [(ch*576 + bid)*256 + pos] =
        ((unsigned long long)(m ^ 0x7FFFFFu) << 32) | (uint32_t)i;
    }
  }
  __syncthreads();
  if (tid < 2) ctl[W_LCNT + tid*576 + bid] = lcnt[tid];
}

// kD (1 block x 1024): gather survivors via LDS-atomic slots (order-free),
// rank-count (no sort, no barrier chains), write labels.
// sk asc == (key desc, idx asc) == argsort rank order; all sk distinct.
__global__ __launch_bounds__(1024) void kD(float* __restrict__ out,
                                           uint32_t* __restrict__ ctl){
  int tid = threadIdx.x;
  __shared__ unsigned long long skey[MAXSURV];   // 16 KB
  __shared__ uint32_t nctr;
  for (int c = 0; c < 2; ++c){
    uint32_t keep    = ctl[W_SEL + c*4 + 1];
    uint32_t keepAll = ctl[W_SEL + c*4 + 2];
    if (!keepAll){
      if (tid == 0) nctr = 0u;
      __syncthreads();
      if (tid < 576){
        uint32_t cnum = ctl[W_LCNT + c*576 + tid];
        if (cnum){
          uint32_t base = atomicAdd(&nctr, cnum);
          const unsigned long long* list =
            reinterpret_cast<const unsigned long long*>(ctl + W_LIST)
            + (size_t)(c*576 + tid)*256;
          for (uint32_t j = 0; j < cnum; ++j){
            uint32_t p = base + j;
            if (p < (uint32_t)MAXSURV) skey[p] = list[j];
          }
        }
      }
      __syncthreads();
      int n = (int)nctr; if (n > MAXSURV) n = MAXSURV;
      float kv = (c == 0) ? 1.0f : 0.0f;
      for (int p = tid; p < n; p += 1024){
        unsigned long long mine = skey[p];
        uint32_t r = 0;
        for (int j = 0; j < n; ++j) r += (skey[j] < mine) ? 1u : 0u;  // LDS broadcast
        uint32_t idx = (uint32_t)(mine & 0xFFFFFFFFull);
        out[idx] = (r < keep) ? kv : -1.0f;
      }
    }
    __syncthreads();
  }
}

extern "C" void kernel_launch(void* const* d_in, const int* in_sizes, int n_in,
                              void* d_out, int out_size, void* d_ws, size_t ws_size,
                              hipStream_t stream) {
  const float* gt   = (const float*)d_in[1];   // (1,128,4)
  const float* meta = (const float*)d_in[2];   // (1,3) = {H, W, scale}
  float* out = (float*)d_out;                  // labels (147456) + targets (147456*4)
  signed char* lab = (signed char*)d_ws;
  uint32_t* keys = (uint32_t*)((char*)d_ws + N_ANCH);
  uint32_t* ctl  = keys + N_ANCH;

  // jax.random.key(42) = (0,42); partitionable split: key_i = enc(0, i) outputs
  uint32_t a0,a1,b0,b1;
  tf2x32(0u, 42u, 0u, 0u, &a0, &a1);   // k1 (positives)
  tf2x32(0u, 42u, 0u, 1u, &b0, &b1);   // k2 (negatives)

  kA<<<1600, 256, 0, stream>>>(gt, meta, lab, keys, ctl, out, a0, a1, b0, b1);
  kC<<<576, 256, 0, stream>>>(lab, keys, out, ctl, a0, a1);
  kD<<<1, 1024, 0, stream>>>(out, ctl);
}

// Round 11
// 53.049 us; speedup vs baseline: 3.3285x; 1.1939x over previous
//
#include <hip/hip_runtime.h>
#include <stdint.h>

#define N_ANCH 147456
#define NGT 128

// d_ws layout: lab (N_ANCH B) | keys (N_ANCH u32) | ctl (u32 words below).
// NOTHING needs zero-init: every word read is unconditionally written earlier
// in the same call by a prior kernel (plain disjoint stores, no atomics).
#define W_CNTS   0      // 576 x {cntPos, cntNeg}
#define W_SEL    1152   // 2ch x 4 {Tf, keep, keepAll, pad}  (written by kC blk0, read by kD)
#define W_GMAX2  1160   // 1024 u64 slots (8B-aligned)
#define W_LCNT   3208   // 2 x 576 survivor counts
#define W_LIST   4360   // 2 x 576 x 256 u64 sortkeys
#define MAXSURV  2048

__constant__ float c_base[9][4] = {
  {-84.f,-40.f,99.f,55.f},     // r=0.5 s=8
  {-176.f,-88.f,191.f,103.f},  // r=0.5 s=16
  {-360.f,-184.f,375.f,199.f}, // r=0.5 s=32
  {-56.f,-56.f,71.f,71.f},     // r=1   s=8
  {-120.f,-120.f,135.f,135.f}, // r=1   s=16
  {-248.f,-248.f,263.f,263.f}, // r=1   s=32
  {-36.f,-80.f,51.f,95.f},     // r=2   s=8
  {-80.f,-168.f,95.f,183.f},   // r=2   s=16
  {-168.f,-344.f,183.f,359.f}, // r=2   s=32
};
// exact per-type anchor areas (W*H, integers < 2^24 -> bitwise == __fmul_rn result)
__constant__ float c_areaA[9] = {
  17664.f, 70656.f, 282624.f,
  16384.f, 65536.f, 262144.f,
  15488.f, 61952.f, 247808.f,
};
// extents over all 9 types: x1min=-360 x2max=375 y1min=-344 y2max=359

__host__ __device__ inline uint32_t rotl32(uint32_t v, int d){ return (v<<d)|(v>>(32-d)); }

// JAX Threefry-2x32, 20 rounds
__host__ __device__ inline void tf2x32(uint32_t k0, uint32_t k1, uint32_t x0, uint32_t x1,
                                       uint32_t* o0, uint32_t* o1){
  uint32_t ks0=k0, ks1=k1, ks2=k0^k1^0x1BD11BDAu;
  x0 += ks0; x1 += ks1;
  #define TFR(r) { x0 += x1; x1 = rotl32(x1,(r)); x1 ^= x0; }
  TFR(13) TFR(15) TFR(26) TFR(6)   x0+=ks1; x1+=ks2+1u;
  TFR(17) TFR(29) TFR(16) TFR(24)  x0+=ks2; x1+=ks0+2u;
  TFR(13) TFR(15) TFR(26) TFR(6)   x0+=ks0; x1+=ks1+3u;
  TFR(17) TFR(29) TFR(16) TFR(24)  x0+=ks1; x1+=ks2+4u;
  TFR(13) TFR(15) TFR(26) TFR(6)   x0+=ks2; x1+=ks0+5u;
  #undef TFR
  *o0=x0; *o1=x1;
}

// jax_threefry_partitionable=True: bits(j) = o0^o1 of enc(0,j); key = top 23 bits
__device__ inline uint32_t rand_m23(uint32_t k0, uint32_t k1, uint32_t j){
  uint32_t a, b;
  tf2x32(k0, k1, 0u, j, &a, &b);
  return (a ^ b) >> 9;
}

// kA: blocks <576: per-anchor labels/keys/targets + per-block counts,
//     scanning only the block-relevant gt list (ballot-compacted, index order).
//     blocks >=576: per-(gt,slice) argmax over the gt's overlap window only.
// IoU bitwise-identical to reference path (areas hoisted, same rounding,
// quick-reject ov=+0 == 0/denom). Argmax edge cases:
//  - all-zero row: best<0 (empty list) -> (0, firstSkipped); best==0 ->
//    arg=min(arg, firstSkipped) == global first index (one side contains 0).
//  - part2: any max-IoU anchor has ov>0 -> inside window; every gt overlaps
//    an inside anchor (56px-margin types vs interior >=16px gts) -> window
//    always contains the winner and all ties; per-thread order ascending-k.
__global__ __launch_bounds__(256) void kA(const float* __restrict__ gt,
                                          const float* __restrict__ meta,
                                          signed char* __restrict__ lab,
                                          uint32_t* __restrict__ keys,
                                          uint32_t* __restrict__ ctl,
                                          float* __restrict__ out,
                                          uint32_t pk0,uint32_t pk1,
                                          uint32_t nk0,uint32_t nk1){
  int bid = blockIdx.x;
  float W = meta[1], H = meta[0];
  if (bid < 576){
    __shared__ float4 sg[NGT];
    __shared__ float  sB[NGT];
    __shared__ uint32_t slist[NGT];
    __shared__ unsigned long long sball[2];
    __shared__ uint32_t c0, c1;
    if (threadIdx.x == 0){ c0 = 0u; c1 = 0u; }
    for (int t = threadIdx.x; t < NGT; t += 256){
      float4 G = reinterpret_cast<const float4*>(gt)[t];
      sg[t] = G;
      sB[t] = __fmul_rn(G.z - G.x + 1.0f, G.w - G.y + 1.0f);
    }
    // block anchor region (all 9 types' extents + 1px float slop)
    int i0 = bid*256, k0 = i0/9, k1 = (i0+255)/9;
    int y0 = k0 >> 7, y1 = k1 >> 7;
    int x0 = (y0==y1) ? (k0 & 127) : 0, x1 = (y0==y1) ? (k1 & 127) : 127;
    float Rxlo = 16.f*x0 - 361.f, Rxhi = 16.f*x1 + 376.f;
    float Rylo = 16.f*y0 - 345.f, Ryhi = 16.f*y1 + 360.f;
    __syncthreads();
    if (threadIdx.x < NGT){
      float4 G = sg[threadIdx.x];
      bool rel = (G.x <= Rxhi) && (G.z >= Rxlo) && (G.y <= Ryhi) && (G.w >= Rylo);
      unsigned long long b = __ballot(rel);
      if ((threadIdx.x & 63) == 0) sball[threadIdx.x >> 6] = b;
    }
    __syncthreads();
    unsigned long long b0 = sball[0], b1 = sball[1];
    if (threadIdx.x < NGT){
      float4 G = sg[threadIdx.x];
      bool rel = (G.x <= Rxhi) && (G.z >= Rxlo) && (G.y <= Ryhi) && (G.w >= Rylo);
      if (rel){
        int lane = threadIdx.x & 63;
        unsigned long long my = (threadIdx.x < 64) ? b0 : b1;
        uint32_t pos = (uint32_t)__popcll(my & ((1ull << lane) - 1ull));
        if (threadIdx.x >= 64) pos += (uint32_t)__popcll(b0);
        slist[pos] = (uint32_t)threadIdx.x;
      }
    }
    __syncthreads();
    int nl = (int)(__popcll(b0) + __popcll(b1));
    int fs;   // first gt index NOT in list (=128 if all in list)
    {
      unsigned long long n0 = ~b0;
      if (n0) fs = __ffsll((long long)n0) - 1;
      else { unsigned long long n1 = ~b1; fs = n1 ? 64 + __ffsll((long long)n1) - 1 : 128; }
    }
    int i = bid*256 + threadIdx.x;
    int k = i / 9; int t9 = i - k*9;
    float sx = 16.0f * (float)(k & 127);
    float sy = 16.0f * (float)(k >> 7);
    float ax1 = c_base[t9][0] + sx, ay1 = c_base[t9][1] + sy;
    float ax2 = c_base[t9][2] + sx, ay2 = c_base[t9][3] + sy;
    float areaA = c_areaA[t9];
    bool inside = (ax1 >= 0.0f) && (ay1 >= 0.0f) && (ax2 < W) && (ay2 < H);
    float best = -1.0f; int arg = 0;   // outside: overlaps all -1 -> argmax 0
    if (inside){
      best = -2.0f;
      for (int li = 0; li < nl; ++li){
        int g = (int)slist[li];
        float4 G = sg[g];
        float iw = fminf(ax2,G.z) - fmaxf(ax1,G.x) + 1.0f;
        float ih = fminf(ay2,G.w) - fmaxf(ay1,G.y) + 1.0f;
        float ov = 0.0f;
        if (iw > 0.0f && ih > 0.0f){
          float inter = __fmul_rn(iw, ih);
          ov = inter / ((areaA + sB[g]) - inter);
        }
        if (ov > best){ best = ov; arg = g; }   // list ascending -> first-occurrence
      }
      if (best < 0.0f){ best = 0.0f; arg = fs; }          // empty list: all-zero row
      else if (best == 0.0f){ arg = (arg < fs) ? arg : fs; } // all-zero row -> idx 0
    }
    signed char L = -1;
    if (best >= 0.7f) L = 1;
    else if (inside && best < 0.3f) L = 0;
    lab[i] = L;
    if (L == 1) keys[i] = rand_m23(pk0,pk1,(uint32_t)i);
    else if (L == 0) keys[i] = rand_m23(nk0,nk1,(uint32_t)i);
    unsigned long long q1 = __ballot(L == 1);
    unsigned long long q0 = __ballot(L == 0);
    if ((threadIdx.x & 63) == 0){
      if (q1) atomicAdd(&c0, (uint32_t)__popcll(q1));
      if (q0) atomicAdd(&c1, (uint32_t)__popcll(q0));
    }
    float4 t4 = make_float4(0.f, 0.f, 0.f, 0.f);
    if (inside){
      float4 G = sg[arg];
      float ew = ax2-ax1+1.0f, eh = ay2-ay1+1.0f;
      float ecx = ax1 + 0.5f*ew, ecy = ay1 + 0.5f*eh;
      float gw = G.z-G.x+1.0f, gh = G.w-G.y+1.0f;
      float gcx = G.x + 0.5f*gw, gcy = G.y + 0.5f*gh;
      t4.x = (gcx-ecx)/ew; t4.y = (gcy-ecy)/eh;
      t4.z = logf(gw/ew);  t4.w = logf(gh/eh);
    }
    *reinterpret_cast<float4*>(out + N_ANCH + 4*(size_t)i) = t4;
    __syncthreads();
    if (threadIdx.x == 0){
      ctl[W_CNTS + 2*bid]     = c0;
      ctl[W_CNTS + 2*bid + 1] = c1;
    }
  } else {
    int b2 = bid - 576;
    int g = b2 >> 3, slice = b2 & 7;
    float bx1=gt[4*g], by1=gt[4*g+1], bx2=gt[4*g+2], by2=gt[4*g+3];
    float areaB = __fmul_rn(bx2-bx1+1.0f, by2-by1+1.0f);
    // overlap-possible position window (+1px float slop)
    int pxl = max(0,   (int)ceilf ((bx1 - 377.0f) * 0.0625f));
    int pxh = min(127, (int)floorf((bx2 + 362.0f) * 0.0625f));
    int pyl = max(0,   (int)ceilf ((by1 - 361.0f) * 0.0625f));
    int pyh = min(127, (int)floorf((by2 + 346.0f) * 0.0625f));
    int Wp = pxh - pxl + 1, tot = Wp * (pyh - pyl + 1);
    float a0[9],a1[9],a2[9],a3[9];
    #pragma unroll
    for (int t=0;t<9;++t){ a0[t]=c_base[t][0]; a1[t]=c_base[t][1];
                           a2[t]=c_base[t][2]; a3[t]=c_base[t][3]; }
    float best = -2.0f; int bi = 0;
    for (int pos = slice*256 + threadIdx.x; pos < tot; pos += 2048){
      int py = pyl + pos / Wp;
      int px = pxl + (pos - (pos / Wp) * Wp);
      int k = (py << 7) + px;           // ascending in pos -> first-occurrence ties
      float sx = 16.0f * (float)px;
      float sy = 16.0f * (float)py;
      #pragma unroll
      for (int t = 0; t < 9; ++t){
        float ax1=a0[t]+sx, ay1=a1[t]+sy, ax2=a2[t]+sx, ay2=a3[t]+sy;
        bool inside = (ax1 >= 0.0f) && (ay1 >= 0.0f) && (ax2 < W) && (ay2 < H);
        float iw = fminf(ax2,bx2) - fmaxf(ax1,bx1) + 1.0f;
        float ih = fminf(ay2,by2) - fmaxf(ay1,by1) + 1.0f;
        float ov = inside ? 0.0f : -1.0f;
        if (inside && iw > 0.0f && ih > 0.0f){
          float inter = __fmul_rn(iw, ih);
          ov = inter / ((c_areaA[t] + areaB) - inter);
        }
        if (ov > best){ best = ov; bi = k*9 + t; }
      }
    }
    unsigned long long p = 0ull;
    if (best >= 0.0f)
      p = ((unsigned long long)__float_as_uint(best) << 32) | (uint32_t)(~(uint32_t)bi);
    __shared__ unsigned long long sred[256];
    sred[threadIdx.x] = p;
    __syncthreads();
    for (int s = 128; s > 0; s >>= 1){
      if ((int)threadIdx.x < s){
        unsigned long long q = sred[threadIdx.x + s];
        if (q > sred[threadIdx.x]) sred[threadIdx.x] = q;
      }
      __syncthreads();
    }
    if (threadIdx.x == 0)
      reinterpret_cast<unsigned long long*>(ctl + W_GMAX2)[b2] = sred[0];
  }
}

// kC: each block redundantly derives the selection state (winners, counts, Tf)
// from kA's outputs (L2-hot ~13KB), applies winners locally via an LDS flag
// table, writes final labels, appends survivors. Block 0 persists W_SEL for kD.
__global__ __launch_bounds__(256) void kC(const signed char* __restrict__ lab,
                                          const uint32_t* __restrict__ keys,
                                          float* __restrict__ out,
                                          uint32_t* __restrict__ ctl,
                                          uint32_t pk0, uint32_t pk1){
  int tid = threadIdx.x, bid = blockIdx.x;
  __shared__ uint32_t widx[NGT], wkey[NGT], wflag[256];
  __shared__ int sdP, sdN;
  __shared__ unsigned long long red[256];
  __shared__ uint32_t sel[6];     // 2ch x {Tf, keep, keepAll}
  __shared__ uint32_t lcnt[2];
  wflag[tid] = 0xFFFFFFFFu;
  if (tid == 0){ sdP = 0; sdN = 0; lcnt[0] = 0u; lcnt[1] = 0u; }
  if (tid < NGT){
    const unsigned long long* g2 =
      reinterpret_cast<const unsigned long long*>(ctl + W_GMAX2);
    unsigned long long best = 0ull;
    #pragma unroll
    for (int s = 0; s < 8; ++s){
      unsigned long long q = g2[tid*8 + s];
      if (q > best) best = q;
    }
    uint32_t idx = best ? ~(uint32_t)best : 0xFFFFFFFFu;
    widx[tid] = idx;
    wkey[tid] = (idx != 0xFFFFFFFFu) ? rand_m23(pk0, pk1, idx) : 0u;
  }
  // per-block counts (packed u64: no cross-carry, sums < 2^32)
  unsigned long long acc = 0ull;
  for (int b = tid; b < 576; b += 256)
    acc += ((unsigned long long)ctl[W_CNTS + 2*b] << 32) | ctl[W_CNTS + 2*b + 1];
  red[tid] = acc;
  __syncthreads();
  for (int s = 128; s > 0; s >>= 1){
    if (tid < s) red[tid] += red[tid + s];
    __syncthreads();
  }
  if (tid < NGT && widx[tid] != 0xFFFFFFFFu){
    uint32_t idx = widx[tid];
    if ((idx >> 8) == (uint32_t)bid) wflag[idx & 255u] = wkey[tid];
    bool resp = true;                     // dedup: first gt owns a shared winner
    for (int g = 0; g < tid; ++g) if (widx[g] == idx){ resp = false; break; }
    if (resp){
      int oldL = lab[idx];
      if (oldL != 1){ atomicAdd(&sdP, 1); if (oldL == 0) atomicAdd(&sdN, 1); }
    }
  }
  __syncthreads();
  if (tid == 0){
    uint32_t cntP = (uint32_t)(red[0] >> 32) + (uint32_t)sdP;
    uint32_t cntN = (uint32_t)red[0] - (uint32_t)sdN;
    uint32_t keepP = cntP < 128u ? cntP : 128u;
    uint32_t keepN = cntN < (256u - keepP) ? cntN : (256u - keepP);
    uint32_t cnts[2] = {cntP, cntN}, keeps[2] = {keepP, keepN};
    for (int c = 0; c < 2; ++c){
      uint32_t cnt = cnts[c], keep = keeps[c];
      uint32_t all = (keep >= cnt) ? 1u : 0u, Tf = 0u;
      if (!all){
        unsigned long long slack = 4ull * keep;   // mean survivors ~4*keep (>=10 sigma)
        if (slack < cnt)
          Tf = (uint32_t)((((unsigned long long)(cnt - slack)) << 23) / cnt);
      }
      sel[c*3+0] = Tf; sel[c*3+1] = keep; sel[c*3+2] = all;
    }
    if (bid == 0){
      for (int c = 0; c < 2; ++c){
        ctl[W_SEL + c*4 + 0] = sel[c*3+0];
        ctl[W_SEL + c*4 + 1] = sel[c*3+1];
        ctl[W_SEL + c*4 + 2] = sel[c*3+2];
      }
    }
  }
  __syncthreads();
  int i = bid*256 + tid;
  int L = lab[i];
  uint32_t wf = wflag[tid];
  uint32_t m = 0u;
  if (wf != 0xFFFFFFFFu){ L = 1; m = wf; }       // winner override (pos channel)
  else if (L >= 0) m = keys[i];
  if (L < 0){
    out[i] = -1.0f;
  } else {
    int ch = (L == 1) ? 0 : 1;
    if (sel[ch*3+2]){
      out[i] = (float)L;
    } else if (m < sel[ch*3+0]){
      out[i] = -1.0f;                      // provably below the cutoff
    } else {
      uint32_t pos = atomicAdd(&lcnt[ch], 1u);
      reinterpret_cast<unsigned long long*>(ctl + W_LIST)
        [(ch*576 + bid)*256 + pos] =
        ((unsigned long long)(m ^ 0x7FFFFFu) << 32) | (uint32_t)i;
    }
  }
  __syncthreads();
  if (tid < 2) ctl[W_LCNT + tid*576 + bid] = lcnt[tid];
}

// kD (1 block x 1024): gather survivors via LDS-atomic slots (order-free),
// rank-count (no sort, no barrier chains), write labels.
// sk asc == (key desc, idx asc) == argsort rank order; all sk distinct.
__global__ __launch_bounds__(1024) void kD(float* __restrict__ out,
                                           uint32_t* __restrict__ ctl){
  int tid = threadIdx.x;
  __shared__ unsigned long long skey[MAXSURV];   // 16 KB
  __shared__ uint32_t nctr;
  for (int c = 0; c < 2; ++c){
    uint32_t keep    = ctl[W_SEL + c*4 + 1];
    uint32_t keepAll = ctl[W_SEL + c*4 + 2];
    if (!keepAll){
      if (tid == 0) nctr = 0u;
      __syncthreads();
      if (tid < 576){
        uint32_t cnum = ctl[W_LCNT + c*576 + tid];
        if (cnum){
          uint32_t base = atomicAdd(&nctr, cnum);
          const unsigned long long* list =
            reinterpret_cast<const unsigned long long*>(ctl + W_LIST)
            + (size_t)(c*576 + tid)*256;
          for (uint32_t j = 0; j < cnum; ++j){
            uint32_t p = base + j;
            if (p < (uint32_t)MAXSURV) skey[p] = list[j];
          }
        }
      }
      __syncthreads();
      int n = (int)nctr; if (n > MAXSURV) n = MAXSURV;
      float kv = (c == 0) ? 1.0f : 0.0f;
      for (int p = tid; p < n; p += 1024){
        unsigned long long mine = skey[p];
        uint32_t r = 0;
        for (int j = 0; j < n; ++j) r += (skey[j] < mine) ? 1u : 0u;  // LDS broadcast
        uint32_t idx = (uint32_t)(mine & 0xFFFFFFFFull);
        out[idx] = (r < keep) ? kv : -1.0f;
      }
    }
    __syncthreads();
  }
}

extern "C" void kernel_launch(void* const* d_in, const int* in_sizes, int n_in,
                              void* d_out, int out_size, void* d_ws, size_t ws_size,
                              hipStream_t stream) {
  const float* gt   = (const float*)d_in[1];   // (1,128,4)
  const float* meta = (const float*)d_in[2];   // (1,3) = {H, W, scale}
  float* out = (float*)d_out;                  // labels (147456) + targets (147456*4)
  signed char* lab = (signed char*)d_ws;
  uint32_t* keys = (uint32_t*)((char*)d_ws + N_ANCH);
  uint32_t* ctl  = keys + N_ANCH;

  // jax.random.key(42) = (0,42); partitionable split: key_i = enc(0, i) outputs
  uint32_t a0,a1,b0,b1;
  tf2x32(0u, 42u, 0u, 0u, &a0, &a1);   // k1 (positives)
  tf2x32(0u, 42u, 0u, 1u, &b0, &b1);   // k2 (negatives)

  kA<<<1600, 256, 0, stream>>>(gt, meta, lab, keys, ctl, out, a0, a1, b0, b1);
  kC<<<576, 256, 0, stream>>>(lab, keys, out, ctl, a0, a1);
  kD<<<1, 1024, 0, stream>>>(out, ctl);
}

// Round 12
// 47.823 us; speedup vs baseline: 3.6922x; 1.1093x over previous
//
#include <hip/hip_runtime.h>
#include <stdint.h>

#define N_ANCH 147456
#define NGT 128

// d_ws layout: lab (N_ANCH B) | keys (N_ANCH u32) | ctl (u32 words below).
// NOTHING needs zero-init: every word read is unconditionally written earlier
// in the same call by a prior kernel (plain disjoint stores, no atomics).
#define W_CNTS   0      // 576 x {cntPos, cntNeg}
#define W_SEL    1152   // 2ch x 4 {Tf, keep, keepAll, pad}  (written by kC blk0, read by kD)
#define W_GMAX2  1160   // 1024 u64 slots (8B-aligned)
#define W_LCNT   3208   // 2 x 576 survivor counts
#define W_LIST   4360   // 2 x 576 x 256 u64 sortkeys
#define MAXSURV  2048

__constant__ float c_base[9][4] = {
  {-84.f,-40.f,99.f,55.f},     // r=0.5 s=8
  {-176.f,-88.f,191.f,103.f},  // r=0.5 s=16
  {-360.f,-184.f,375.f,199.f}, // r=0.5 s=32
  {-56.f,-56.f,71.f,71.f},     // r=1   s=8
  {-120.f,-120.f,135.f,135.f}, // r=1   s=16
  {-248.f,-248.f,263.f,263.f}, // r=1   s=32
  {-36.f,-80.f,51.f,95.f},     // r=2   s=8
  {-80.f,-168.f,95.f,183.f},   // r=2   s=16
  {-168.f,-344.f,183.f,359.f}, // r=2   s=32
};
// exact per-type anchor areas (W*H, integers < 2^24 -> bitwise == __fmul_rn result)
__constant__ float c_areaA[9] = {
  17664.f, 70656.f, 282624.f,
  16384.f, 65536.f, 262144.f,
  15488.f, 61952.f, 247808.f,
};
// extents over all 9 types: x1min=-360 x2max=375 y1min=-344 y2max=359

__host__ __device__ inline uint32_t rotl32(uint32_t v, int d){ return (v<<d)|(v>>(32-d)); }

// JAX Threefry-2x32, 20 rounds
__host__ __device__ inline void tf2x32(uint32_t k0, uint32_t k1, uint32_t x0, uint32_t x1,
                                       uint32_t* o0, uint32_t* o1){
  uint32_t ks0=k0, ks1=k1, ks2=k0^k1^0x1BD11BDAu;
  x0 += ks0; x1 += ks1;
  #define TFR(r) { x0 += x1; x1 = rotl32(x1,(r)); x1 ^= x0; }
  TFR(13) TFR(15) TFR(26) TFR(6)   x0+=ks1; x1+=ks2+1u;
  TFR(17) TFR(29) TFR(16) TFR(24)  x0+=ks2; x1+=ks0+2u;
  TFR(13) TFR(15) TFR(26) TFR(6)   x0+=ks0; x1+=ks1+3u;
  TFR(17) TFR(29) TFR(16) TFR(24)  x0+=ks1; x1+=ks2+4u;
  TFR(13) TFR(15) TFR(26) TFR(6)   x0+=ks2; x1+=ks0+5u;
  #undef TFR
  *o0=x0; *o1=x1;
}

// jax_threefry_partitionable=True: bits(j) = o0^o1 of enc(0,j); key = top 23 bits
__device__ inline uint32_t rand_m23(uint32_t k0, uint32_t k1, uint32_t j){
  uint32_t a, b;
  tf2x32(k0, k1, 0u, j, &a, &b);
  return (a ^ b) >> 9;
}

// kA: blocks <576: per-anchor labels/keys/targets + per-block counts,
//     scanning only the block-relevant gt list (ballot-compacted, index order).
//     blocks >=576: per-(gt,slice) argmax over the gt's overlap window only.
// IoU bitwise-identical to reference path (areas hoisted, same rounding,
// quick-reject ov=+0 == 0/denom).
__global__ __launch_bounds__(256) void kA(const float* __restrict__ gt,
                                          const float* __restrict__ meta,
                                          signed char* __restrict__ lab,
                                          uint32_t* __restrict__ keys,
                                          uint32_t* __restrict__ ctl,
                                          float* __restrict__ out,
                                          uint32_t pk0,uint32_t pk1,
                                          uint32_t nk0,uint32_t nk1){
  int bid = blockIdx.x;
  float W = meta[1], H = meta[0];
  if (bid < 576){
    __shared__ float4 sg[NGT];
    __shared__ float  sB[NGT];
    __shared__ uint32_t slist[NGT];
    __shared__ unsigned long long sball[2];
    __shared__ uint32_t c0, c1;
    if (threadIdx.x == 0){ c0 = 0u; c1 = 0u; }
    for (int t = threadIdx.x; t < NGT; t += 256){
      float4 G = reinterpret_cast<const float4*>(gt)[t];
      sg[t] = G;
      sB[t] = __fmul_rn(G.z - G.x + 1.0f, G.w - G.y + 1.0f);
    }
    // block anchor region (all 9 types' extents + 1px float slop)
    int i0 = bid*256, k0 = i0/9, k1 = (i0+255)/9;
    int y0 = k0 >> 7, y1 = k1 >> 7;
    int x0 = (y0==y1) ? (k0 & 127) : 0, x1 = (y0==y1) ? (k1 & 127) : 127;
    float Rxlo = 16.f*x0 - 361.f, Rxhi = 16.f*x1 + 376.f;
    float Rylo = 16.f*y0 - 345.f, Ryhi = 16.f*y1 + 360.f;
    __syncthreads();
    if (threadIdx.x < NGT){
      float4 G = sg[threadIdx.x];
      bool rel = (G.x <= Rxhi) && (G.z >= Rxlo) && (G.y <= Ryhi) && (G.w >= Rylo);
      unsigned long long b = __ballot(rel);
      if ((threadIdx.x & 63) == 0) sball[threadIdx.x >> 6] = b;
    }
    __syncthreads();
    unsigned long long b0 = sball[0], b1 = sball[1];
    if (threadIdx.x < NGT){
      float4 G = sg[threadIdx.x];
      bool rel = (G.x <= Rxhi) && (G.z >= Rxlo) && (G.y <= Ryhi) && (G.w >= Rylo);
      if (rel){
        int lane = threadIdx.x & 63;
        unsigned long long my = (threadIdx.x < 64) ? b0 : b1;
        uint32_t pos = (uint32_t)__popcll(my & ((1ull << lane) - 1ull));
        if (threadIdx.x >= 64) pos += (uint32_t)__popcll(b0);
        slist[pos] = (uint32_t)threadIdx.x;
      }
    }
    __syncthreads();
    int nl = (int)(__popcll(b0) + __popcll(b1));
    int fs;   // first gt index NOT in list (=128 if all in list)
    {
      unsigned long long n0 = ~b0;
      if (n0) fs = __ffsll((long long)n0) - 1;
      else { unsigned long long n1 = ~b1; fs = n1 ? 64 + __ffsll((long long)n1) - 1 : 128; }
    }
    int i = bid*256 + threadIdx.x;
    int k = i / 9; int t9 = i - k*9;
    float sx = 16.0f * (float)(k & 127);
    float sy = 16.0f * (float)(k >> 7);
    float ax1 = c_base[t9][0] + sx, ay1 = c_base[t9][1] + sy;
    float ax2 = c_base[t9][2] + sx, ay2 = c_base[t9][3] + sy;
    float areaA = c_areaA[t9];
    bool inside = (ax1 >= 0.0f) && (ay1 >= 0.0f) && (ax2 < W) && (ay2 < H);
    float best = -1.0f; int arg = 0;   // outside: overlaps all -1 -> argmax 0
    if (inside){
      best = -2.0f;
      for (int li = 0; li < nl; ++li){
        int g = (int)slist[li];
        float4 G = sg[g];
        float iw = fminf(ax2,G.z) - fmaxf(ax1,G.x) + 1.0f;
        float ih = fminf(ay2,G.w) - fmaxf(ay1,G.y) + 1.0f;
        float ov = 0.0f;
        if (iw > 0.0f && ih > 0.0f){
          float inter = __fmul_rn(iw, ih);
          ov = inter / ((areaA + sB[g]) - inter);
        }
        if (ov > best){ best = ov; arg = g; }   // list ascending -> first-occurrence
      }
      if (best < 0.0f){ best = 0.0f; arg = fs; }          // empty list: all-zero row
      else if (best == 0.0f){ arg = (arg < fs) ? arg : fs; } // all-zero row -> idx 0
    }
    signed char L = -1;
    if (best >= 0.7f) L = 1;
    else if (inside && best < 0.3f) L = 0;
    lab[i] = L;
    if (L == 1) keys[i] = rand_m23(pk0,pk1,(uint32_t)i);
    else if (L == 0) keys[i] = rand_m23(nk0,nk1,(uint32_t)i);
    unsigned long long q1 = __ballot(L == 1);
    unsigned long long q0 = __ballot(L == 0);
    if ((threadIdx.x & 63) == 0){
      if (q1) atomicAdd(&c0, (uint32_t)__popcll(q1));
      if (q0) atomicAdd(&c1, (uint32_t)__popcll(q0));
    }
    float4 t4 = make_float4(0.f, 0.f, 0.f, 0.f);
    if (inside){
      float4 G = sg[arg];
      float ew = ax2-ax1+1.0f, eh = ay2-ay1+1.0f;
      float ecx = ax1 + 0.5f*ew, ecy = ay1 + 0.5f*eh;
      float gw = G.z-G.x+1.0f, gh = G.w-G.y+1.0f;
      float gcx = G.x + 0.5f*gw, gcy = G.y + 0.5f*gh;
      t4.x = (gcx-ecx)/ew; t4.y = (gcy-ecy)/eh;
      t4.z = logf(gw/ew);  t4.w = logf(gh/eh);
    }
    *reinterpret_cast<float4*>(out + N_ANCH + 4*(size_t)i) = t4;
    __syncthreads();
    if (threadIdx.x == 0){
      ctl[W_CNTS + 2*bid]     = c0;
      ctl[W_CNTS + 2*bid + 1] = c1;
    }
  } else {
    int b2 = bid - 576;
    int g = b2 >> 3, slice = b2 & 7;
    float bx1=gt[4*g], by1=gt[4*g+1], bx2=gt[4*g+2], by2=gt[4*g+3];
    float areaB = __fmul_rn(bx2-bx1+1.0f, by2-by1+1.0f);
    // overlap-possible position window (+1px float slop)
    int pxl = max(0,   (int)ceilf ((bx1 - 377.0f) * 0.0625f));
    int pxh = min(127, (int)floorf((bx2 + 362.0f) * 0.0625f));
    int pyl = max(0,   (int)ceilf ((by1 - 361.0f) * 0.0625f));
    int pyh = min(127, (int)floorf((by2 + 346.0f) * 0.0625f));
    uint32_t Wp = (uint32_t)(pxh - pxl + 1);
    int tot = (int)Wp * (pyh - pyl + 1);
    // magic division: m = ceil(2^22/Wp); exact for Wp<=128, pos<=16383
    uint32_t mdiv = (4194304u + Wp - 1u) / Wp;
    float a0[9],a1[9],a2[9],a3[9];
    #pragma unroll
    for (int t=0;t<9;++t){ a0[t]=c_base[t][0]; a1[t]=c_base[t][1];
                           a2[t]=c_base[t][2]; a3[t]=c_base[t][3]; }
    float best = -2.0f; int bi = 0;
    for (int pos = slice*256 + threadIdx.x; pos < tot; pos += 2048){
      uint32_t dq = (uint32_t)(((unsigned long long)(uint32_t)pos * mdiv) >> 22);
      int py = pyl + (int)dq;
      int px = pxl + (int)((uint32_t)pos - dq * Wp);
      int k = (py << 7) + px;           // ascending in pos -> first-occurrence ties
      float sx = 16.0f * (float)px;
      float sy = 16.0f * (float)py;
      #pragma unroll
      for (int t = 0; t < 9; ++t){
        float ax1=a0[t]+sx, ay1=a1[t]+sy, ax2=a2[t]+sx, ay2=a3[t]+sy;
        bool inside = (ax1 >= 0.0f) && (ay1 >= 0.0f) && (ax2 < W) && (ay2 < H);
        float iw = fminf(ax2,bx2) - fmaxf(ax1,bx1) + 1.0f;
        float ih = fminf(ay2,by2) - fmaxf(ay1,by1) + 1.0f;
        float ov = inside ? 0.0f : -1.0f;
        if (inside && iw > 0.0f && ih > 0.0f){
          float inter = __fmul_rn(iw, ih);
          ov = inter / ((c_areaA[t] + areaB) - inter);
        }
        if (ov > best){ best = ov; bi = k*9 + t; }
      }
    }
    unsigned long long p = 0ull;
    if (best >= 0.0f)
      p = ((unsigned long long)__float_as_uint(best) << 32) | (uint32_t)(~(uint32_t)bi);
    __shared__ unsigned long long sred[256];
    sred[threadIdx.x] = p;
    __syncthreads();
    for (int s = 128; s > 0; s >>= 1){
      if ((int)threadIdx.x < s){
        unsigned long long q = sred[threadIdx.x + s];
        if (q > sred[threadIdx.x]) sred[threadIdx.x] = q;
      }
      __syncthreads();
    }
    if (threadIdx.x == 0)
      reinterpret_cast<unsigned long long*>(ctl + W_GMAX2)[b2] = sred[0];
  }
}

// kC: each block redundantly derives the selection state (winners, counts, Tf)
// from kA's outputs (L2-hot ~13KB), applies winners locally via an LDS flag
// table, writes final labels, appends survivors. Block 0 persists W_SEL for kD.
__global__ __launch_bounds__(256) void kC(const signed char* __restrict__ lab,
                                          const uint32_t* __restrict__ keys,
                                          float* __restrict__ out,
                                          uint32_t* __restrict__ ctl,
                                          uint32_t pk0, uint32_t pk1){
  int tid = threadIdx.x, bid = blockIdx.x;
  __shared__ uint32_t widx[NGT], wkey[NGT], wflag[256];
  __shared__ int sdP, sdN;
  __shared__ unsigned long long red[256];
  __shared__ uint32_t sel[6];     // 2ch x {Tf, keep, keepAll}
  __shared__ uint32_t lcnt[2];
  wflag[tid] = 0xFFFFFFFFu;
  if (tid == 0){ sdP = 0; sdN = 0; lcnt[0] = 0u; lcnt[1] = 0u; }
  if (tid < NGT){
    const unsigned long long* g2 =
      reinterpret_cast<const unsigned long long*>(ctl + W_GMAX2);
    unsigned long long best = 0ull;
    #pragma unroll
    for (int s = 0; s < 8; ++s){
      unsigned long long q = g2[tid*8 + s];
      if (q > best) best = q;
    }
    uint32_t idx = best ? ~(uint32_t)best : 0xFFFFFFFFu;
    widx[tid] = idx;
    wkey[tid] = (idx != 0xFFFFFFFFu) ? rand_m23(pk0, pk1, idx) : 0u;
  }
  // per-block counts (packed u64: no cross-carry, sums < 2^32)
  unsigned long long acc = 0ull;
  for (int b = tid; b < 576; b += 256)
    acc += ((unsigned long long)ctl[W_CNTS + 2*b] << 32) | ctl[W_CNTS + 2*b + 1];
  red[tid] = acc;
  __syncthreads();
  for (int s = 128; s > 0; s >>= 1){
    if (tid < s) red[tid] += red[tid + s];
    __syncthreads();
  }
  if (tid < NGT && widx[tid] != 0xFFFFFFFFu){
    uint32_t idx = widx[tid];
    if ((idx >> 8) == (uint32_t)bid) wflag[idx & 255u] = wkey[tid];
    bool resp = true;                     // dedup: first gt owns a shared winner
    for (int g = 0; g < tid; ++g) if (widx[g] == idx){ resp = false; break; }
    if (resp){
      int oldL = lab[idx];
      if (oldL != 1){ atomicAdd(&sdP, 1); if (oldL == 0) atomicAdd(&sdN, 1); }
    }
  }
  __syncthreads();
  if (tid == 0){
    uint32_t cntP = (uint32_t)(red[0] >> 32) + (uint32_t)sdP;
    uint32_t cntN = (uint32_t)red[0] - (uint32_t)sdN;
    uint32_t keepP = cntP < 128u ? cntP : 128u;
    uint32_t keepN = cntN < (256u - keepP) ? cntN : (256u - keepP);
    uint32_t cnts[2] = {cntP, cntN}, keeps[2] = {keepP, keepN};
    for (int c = 0; c < 2; ++c){
      uint32_t cnt = cnts[c], keep = keeps[c];
      uint32_t all = (keep >= cnt) ? 1u : 0u, Tf = 0u;
      if (!all){
        unsigned long long slack = 2ull * keep;   // mean survivors ~2*keep (>=8 sigma:
        if (slack < cnt)                          // keep>=128 in any non-keepAll ch)
          Tf = (uint32_t)((((unsigned long long)(cnt - slack)) << 23) / cnt);
      }
      sel[c*3+0] = Tf; sel[c*3+1] = keep; sel[c*3+2] = all;
    }
    if (bid == 0){
      for (int c = 0; c < 2; ++c){
        ctl[W_SEL + c*4 + 0] = sel[c*3+0];
        ctl[W_SEL + c*4 + 1] = sel[c*3+1];
        ctl[W_SEL + c*4 + 2] = sel[c*3+2];
      }
    }
  }
  __syncthreads();
  int i = bid*256 + tid;
  int L = lab[i];
  uint32_t wf = wflag[tid];
  uint32_t m = 0u;
  if (wf != 0xFFFFFFFFu){ L = 1; m = wf; }       // winner override (pos channel)
  else if (L >= 0) m = keys[i];
  if (L < 0){
    out[i] = -1.0f;
  } else {
    int ch = (L == 1) ? 0 : 1;
    if (sel[ch*3+2]){
      out[i] = (float)L;
    } else if (m < sel[ch*3+0]){
      out[i] = -1.0f;                      // provably below the cutoff
    } else {
      uint32_t pos = atomicAdd(&lcnt[ch], 1u);
      reinterpret_cast<unsigned long long*>(ctl + W_LIST)
        [(ch*576 + bid)*256 + pos] =
        ((unsigned long long)(m ^ 0x7FFFFFu) << 32) | (uint32_t)i;
    }
  }
  __syncthreads();
  if (tid < 2) ctl[W_LCNT + tid*576 + bid] = lcnt[tid];
}

// kD (1 block x 1024): gather survivors via parallel prefix scan (no
// same-address LDS atomics), rank-count (no sort), write labels.
// sk asc == (key desc, idx asc) == argsort rank order; all sk distinct.
__global__ __launch_bounds__(1024) void kD(float* __restrict__ out,
                                           uint32_t* __restrict__ ctl){
  int tid = threadIdx.x;
  __shared__ unsigned long long skey[MAXSURV];   // 16 KB
  __shared__ uint32_t scan[1024];                // 4 KB
  for (int c = 0; c < 2; ++c){
    uint32_t keep    = ctl[W_SEL + c*4 + 1];
    uint32_t keepAll = ctl[W_SEL + c*4 + 2];
    if (!keepAll){
      uint32_t cnum = (tid < 576) ? ctl[W_LCNT + c*576 + tid] : 0u;
      scan[tid] = cnum;
      __syncthreads();
      // Hillis-Steele inclusive scan over 1024 entries
      for (int off = 1; off < 1024; off <<= 1){
        uint32_t v = (tid >= off) ? scan[tid - off] : 0u;
        __syncthreads();
        scan[tid] += v;
        __syncthreads();
      }
      int n = (int)scan[1023]; if (n > MAXSURV) n = MAXSURV;
      if (cnum){
        uint32_t base = scan[tid] - cnum;   // exclusive prefix
        const unsigned long long* list =
          reinterpret_cast<const unsigned long long*>(ctl + W_LIST)
          + (size_t)(c*576 + tid)*256;
        for (uint32_t j = 0; j < cnum; ++j){
          uint32_t p = base + j;
          if (p < (uint32_t)MAXSURV) skey[p] = list[j];
        }
      }
      __syncthreads();
      float kv = (c == 0) ? 1.0f : 0.0f;
      for (int p = tid; p < n; p += 1024){
        unsigned long long mine = skey[p];
        uint32_t r = 0;
        for (int j = 0; j < n; ++j) r += (skey[j] < mine) ? 1u : 0u;  // LDS broadcast
        uint32_t idx = (uint32_t)(mine & 0xFFFFFFFFull);
        out[idx] = (r < keep) ? kv : -1.0f;
      }
    }
    __syncthreads();
  }
}

extern "C" void kernel_launch(void* const* d_in, const int* in_sizes, int n_in,
                              void* d_out, int out_size, void* d_ws, size_t ws_size,
                              hipStream_t stream) {
  const float* gt   = (const float*)d_in[1];   // (1,128,4)
  const float* meta = (const float*)d_in[2];   // (1,3) = {H, W, scale}
  float* out = (float*)d_out;                  // labels (147456) + targets (147456*4)
  signed char* lab = (signed char*)d_ws;
  uint32_t* keys = (uint32_t*)((char*)d_ws + N_ANCH);
  uint32_t* ctl  = keys + N_ANCH;

  // jax.random.key(42) = (0,42); partitionable split: key_i = enc(0, i) outputs
  uint32_t a0,a1,b0,b1;
  tf2x32(0u, 42u, 0u, 0u, &a0, &a1);   // k1 (positives)
  tf2x32(0u, 42u, 0u, 1u, &b0, &b1);   // k2 (negatives)

  kA<<<1600, 256, 0, stream>>>(gt, meta, lab, keys, ctl, out, a0, a1, b0, b1);
  kC<<<576, 256, 0, stream>>>(lab, keys, out, ctl, a0, a1);
  kD<<<1, 1024, 0, stream>>>(out, ctl);
}